// Round 9
// baseline (417.153 us; speedup 1.0000x reference)
//
#include <hip/hip_runtime.h>
#include <math.h>

// GAT 3-layer forward on MI355X.
// N=50000 nodes, E=850000 edges (incl self loops), IN=128, HID=OUT=32, HEADS=(4,4,6).
// GEMMs: split-f16 MFMA (hi/lo, 3 mfma), LDS-free; A and B pre-packed in MFMA-fragment
// order (pack_off) -> every wave load is 1KB contiguous. NEVER partial-unroll the tile
// loop (dynamic acc[] indexing -> scratch spill, round 4).
// Layer-3 residual+bias folded THROUGH the head-mean: resm = mean_h(resW3 slices) is 2
// extra B-tiles in mfma_fc3; fc3 writes res_m + mean_h(b3) DIRECTLY into d_out (full
// overwrite -> replay-idempotent); layer-3 agg ADDS the softmax mean (plain stores).
// ROUND-3 LESSON: NEVER use global fp32 atomicAdd for the head-mean (300MB WRITE, 4.5x).
// ROUND-4 LESSON: layer-3 gather must be INTERLEAVED [N][192]; head planes only pay
// when the per-XCD working set is L2-resident (L1/L2 agg).
// ROUND-5 LESSON: gather limiter = INDEPENDENT requests in flight; dependent chains
// (csr->el->exp->feat) throttle issue. wexp[E][6] precompute fixed layer-3 agg.
// ROUND-6/7/8 LESSON: returning-atomic sweep is parallelism-bound (4 edges/thread
// shrank the grid and REGRESSED); do the returning atomic ONCE (hist_rank keeps the
// return as in-bucket rank), fill is then ZERO-atomic (row_start[d]+rank[i], int2
// packed scatter = 1 random 64B sector/edge). Round 8: 446->404us.
// ROUND-9: deeper unroll on all gather loops (mean6w 4->6x, agg_q 2->4x) -- with the
// dependent chain gone (wexp), in-flight gather count is the remaining lever (round-4
// evidence: more independent sectors -> 3.57TB/s). Keep VGPR <= 64 (8 waves/SIMD).
// Aggregation L1/L2: QUARTER-WAVE head-split (16 lanes/(node,head), 4 lanes/edge, G=4),
// feat head planes [H][N][32] f16 + el/er planes [H][N], XCD-pinned (blockIdx%8 -> XCD,
// head-major order) -> compulsory fetch. Round-1 lesson: 1 wave/(node,head) = 4x waves
// = overhead-bound. All cross-lane shuffles execute unconditionally (round 9 lesson);
// stores guarded. CSR prefix scan: 3-phase multi-block.

typedef _Float16 v8h __attribute__((ext_vector_type(8)));
typedef float f32x4 __attribute__((ext_vector_type(4)));

// packed fragment offset for row n, k-dim k (128-wide K):
__device__ __host__ inline int pack_off(int n, int k) {
    return ((n >> 4) << 11) | ((k >> 5) << 9) | (((k >> 3) & 3) << 7) | ((n & 15) << 3) | (k & 7);
}

// ---------------- CSR build (by dst) ----------------

// ONE returning-atomic pass: deg histogram AND per-edge in-bucket rank.
__global__ void hist_rank(const int* __restrict__ dst, int E,
                          int* __restrict__ deg, int* __restrict__ rank) {
    int i = blockIdx.x * blockDim.x + threadIdx.x;
    if (i < E) rank[i] = atomicAdd(&deg[dst[i]], 1);
}

__global__ void scan_phaseA(const int* __restrict__ deg, int n, int* __restrict__ bsum) {
    __shared__ int red[4];
    int t = threadIdx.x;
    int base = blockIdx.x * 2048 + t * 8;
    int s = 0;
    #pragma unroll
    for (int q = 0; q < 8; q++) { int i = base + q; if (i < n) s += deg[i]; }
    #pragma unroll
    for (int off = 1; off < 64; off <<= 1) s += __shfl_xor(s, off);
    if ((t & 63) == 0) red[t >> 6] = s;
    __syncthreads();
    if (t == 0) bsum[blockIdx.x] = red[0] + red[1] + red[2] + red[3];
}

__global__ void scan_phaseB(int* __restrict__ bsum, int nb) {
    int lane = threadIdx.x & 63;
    int v = (lane < nb) ? bsum[lane] : 0;
    int inc = v;
    #pragma unroll
    for (int off = 1; off < 64; off <<= 1) {
        int u = __shfl_up(inc, off);
        if (lane >= off) inc += u;
    }
    int ex = inc - v;
    if (lane < nb) bsum[lane] = ex;
}

__global__ void scan_phaseC(const int* __restrict__ deg, int n, const int* __restrict__ bsum,
                            int* __restrict__ row_start, int E) {
    __shared__ int wsum[4];
    int t = threadIdx.x;
    int lane = t & 63, wv = t >> 6;
    int base = blockIdx.x * 2048 + t * 8;
    int v[8]; int s = 0;
    #pragma unroll
    for (int q = 0; q < 8; q++) { int i = base + q; v[q] = (i < n) ? deg[i] : 0; s += v[q]; }
    int inc = s;
    #pragma unroll
    for (int off = 1; off < 64; off <<= 1) {
        int u = __shfl_up(inc, off);
        if (lane >= off) inc += u;
    }
    if (lane == 63) wsum[wv] = inc;
    __syncthreads();
    int woff = 0;
    for (int w = 0; w < wv; w++) woff += wsum[w];
    int run = inc - s + woff + bsum[blockIdx.x];
    #pragma unroll
    for (int q = 0; q < 8; q++) {
        int i = base + q;
        if (i < n) row_start[i] = run;
        run += v[q];
    }
    if (blockIdx.x == 0 && t == 0) row_start[n] = E;
}

// ZERO-atomic fill: position = row_start[d] (L2-resident gather) + rank[i] (stream).
// Single packed int2 scattered store (1 random 64B sector per edge).
__global__ void fill_kernel(const int* __restrict__ src, const int* __restrict__ dst, int E,
                            const int* __restrict__ row_start, const int* __restrict__ rank,
                            int2* __restrict__ csr_sd) {
    int i = blockIdx.x * blockDim.x + threadIdx.x;
    if (i < E) {
        int s = src[i], d = dst[i];
        int at = row_start[d] + rank[i];
        csr_sd[at] = make_int2(s, d);
    }
}

// ---------------- weight hi/lo split into PACKED fragment layout ----------------
// Regions: W1 (128c x 128k), W2 (128c x 128k), B3 = [W3 192c | resm 32c] x 128k.
// resm[k][c] = mean over 6 heads of resW3[k][h*32+c]  (residual folded through head-mean).

__global__ void wsplit_all(const float* __restrict__ W1, const float* __restrict__ W2,
                           const float* __restrict__ W3, const float* __restrict__ Wr,
                           _Float16* __restrict__ o) {
    int i = blockIdx.x * blockDim.x + threadIdx.x;
    if (i >= 61440) return;
    float v; int ohi, stride, po;
    if (i < 16384) {
        int e = i, c = e >> 7, k = e & 127;
        v = W1[(size_t)k * 128 + c]; ohi = 0; stride = 16384; po = pack_off(c, k);
    } else if (i < 32768) {
        int e = i - 16384, c = e >> 7, k = e & 127;
        v = W2[(size_t)k * 128 + c]; ohi = 32768; stride = 16384; po = pack_off(c, k);
    } else if (i < 57344) {
        int e = i - 32768, c = e >> 7, k = e & 127;
        v = W3[(size_t)k * 192 + c]; ohi = 65536; stride = 28672; po = pack_off(c, k);
    } else {
        int e = i - 57344, c = e >> 7, k = e & 127;
        float s = 0.f;
        #pragma unroll
        for (int h = 0; h < 6; h++) s += Wr[(size_t)k * 192 + h * 32 + c];
        v = s * (1.0f / 6.0f);
        ohi = 65536; stride = 28672; po = 24576 + pack_off(c, k);
    }
    _Float16 hv = (_Float16)v;
    o[ohi + po] = hv;
    o[ohi + stride + po] = (_Float16)(v - (float)hv);
}

// ---------------- x -> packed hi/lo f16 fragment layout ----------------

__global__ void splitx_kernel(const float* __restrict__ x, _Float16* __restrict__ hi,
                              _Float16* __restrict__ lo, int N, int PT) {
    int i = blockIdx.x * blockDim.x + threadIdx.x;
    if (i >= PT * 2048) return;
    int mt = i >> 11, r = i & 2047;
    int q4 = r >> 9, quad = (r >> 7) & 3, ln = (r >> 3) & 15, j = r & 7;
    int n = mt * 16 + ln, k = q4 * 32 + quad * 8 + j;
    float v = (n < N) ? x[(size_t)n * 128 + k] : 0.f;
    _Float16 h = (_Float16)v;
    hi[i] = h;
    lo[i] = (_Float16)(v - (float)h);
}

// ---------------- LDS-free MFMA fc (+ attention logits), layers 1/2 ----------------
// feat_out is HEAD-MAJOR PLANES: [H][N][32] f16; el/er are planes [H][N].

template <int CC, int H>
__global__ __launch_bounds__(256, 4) void mfma_fc(
    const _Float16* __restrict__ Ahi, const _Float16* __restrict__ Alo,
    const _Float16* __restrict__ Bhi, const _Float16* __restrict__ Blo,
    const float* __restrict__ al, const float* __restrict__ ar,
    _Float16* __restrict__ feat_out,
    float* __restrict__ el, float* __restrict__ er, int N) {
    constexpr int TILES = CC / 16;
    int t = threadIdx.x;
    int wave = t >> 6, lane = t & 63;
    int ln = lane & 15, quad = lane >> 4;
    int mt = blockIdx.x * 4 + wave;

    f32x4 acc[TILES];
    #pragma unroll
    for (int i = 0; i < TILES; i++) acc[i] = (f32x4){0.f, 0.f, 0.f, 0.f};

    const _Float16* pa_h = Ahi + (size_t)mt * 2048 + lane * 8;
    const _Float16* pa_l = Alo + (size_t)mt * 2048 + lane * 8;

    #pragma unroll
    for (int q4 = 0; q4 < 4; q4++) {
        v8h ah = *(const v8h*)(pa_h + q4 * 512);
        v8h av = *(const v8h*)(pa_l + q4 * 512);
        #pragma unroll
        for (int tt = 0; tt < TILES; tt++) {
            size_t boff = (size_t)tt * 2048 + q4 * 512 + lane * 8;
            v8h bh = *(const v8h*)(Bhi + boff);
            v8h bl = *(const v8h*)(Blo + boff);
            acc[tt] = __builtin_amdgcn_mfma_f32_16x16x32_f16(av, bh, acc[tt], 0, 0, 0);
            acc[tt] = __builtin_amdgcn_mfma_f32_16x16x32_f16(ah, bl, acc[tt], 0, 0, 0);
            acc[tt] = __builtin_amdgcn_mfma_f32_16x16x32_f16(ah, bh, acc[tt], 0, 0, 0);
        }
    }

    #pragma unroll
    for (int tt = 0; tt < TILES; tt++) {
        int n = tt * 16 + ln;
        int head = n >> 5, wi = n & 31;
        _Float16* fo = feat_out + (size_t)head * N * 32;
        #pragma unroll
        for (int r = 0; r < 4; r++) {
            int m = mt * 16 + quad * 4 + r;
            if (m < N) fo[(size_t)m * 32 + wi] = (_Float16)acc[tt][r];
        }
    }
    #pragma unroll
    for (int hg = 0; hg < H; hg++) {
        float a0 = al[hg * 32 + ln], a1 = al[hg * 32 + 16 + ln];
        float r0 = ar[hg * 32 + ln], r1 = ar[hg * 32 + 16 + ln];
        #pragma unroll
        for (int r = 0; r < 4; r++) {
            float pl = acc[2 * hg][r] * a0 + acc[2 * hg + 1][r] * a1;
            float pr = acc[2 * hg][r] * r0 + acc[2 * hg + 1][r] * r1;
            #pragma unroll
            for (int off = 1; off < 16; off <<= 1) {
                pl += __shfl_xor(pl, off);
                pr += __shfl_xor(pr, off);
            }
            int m = mt * 16 + quad * 4 + r;
            if (ln == 0 && m < N) {
                el[(size_t)hg * N + m] = pl;
                er[(size_t)hg * N + m] = pr;
            }
        }
    }
}

// ---------------- layer 3: single pass, 14 tiles ----------------
// Tiles 0..11 = W3 feat -> INTERLEAVED [N][192] f16 (round-4 lesson). Tiles 12..13 =
// res-mean fp32, written (+ mean_h(b3)) DIRECTLY into d_out; agg then ADDS softmax mean.
// Logits go to PADDED [N][8] tables el8/er8 (32B rows, L2-resident for wexp_l3).

__global__ __launch_bounds__(256, 3) void mfma_fc3(
    const _Float16* __restrict__ Ahi, const _Float16* __restrict__ Alo,
    const _Float16* __restrict__ Bhi, const _Float16* __restrict__ Blo,
    const float* __restrict__ al, const float* __restrict__ ar,
    const float* __restrict__ b3,
    _Float16* __restrict__ feat_out, float* __restrict__ out,
    float* __restrict__ el8, float* __restrict__ er8, int N) {
    constexpr int H = 6, TILES = 14;
    int t = threadIdx.x;
    int wave = t >> 6, lane = t & 63;
    int ln = lane & 15, quad = lane >> 4;
    int mt = blockIdx.x * 4 + wave;

    f32x4 acc[TILES];
    #pragma unroll
    for (int i = 0; i < TILES; i++) acc[i] = (f32x4){0.f, 0.f, 0.f, 0.f};

    const _Float16* pa_h = Ahi + (size_t)mt * 2048 + lane * 8;
    const _Float16* pa_l = Alo + (size_t)mt * 2048 + lane * 8;

    #pragma unroll
    for (int q4 = 0; q4 < 4; q4++) {
        v8h ah = *(const v8h*)(pa_h + q4 * 512);
        v8h av = *(const v8h*)(pa_l + q4 * 512);
        #pragma unroll
        for (int tt = 0; tt < TILES; tt++) {
            size_t boff = (size_t)tt * 2048 + q4 * 512 + lane * 8;
            v8h bh = *(const v8h*)(Bhi + boff);
            v8h bl = *(const v8h*)(Blo + boff);
            acc[tt] = __builtin_amdgcn_mfma_f32_16x16x32_f16(av, bh, acc[tt], 0, 0, 0);
            acc[tt] = __builtin_amdgcn_mfma_f32_16x16x32_f16(ah, bl, acc[tt], 0, 0, 0);
            acc[tt] = __builtin_amdgcn_mfma_f32_16x16x32_f16(ah, bh, acc[tt], 0, 0, 0);
        }
    }

    #pragma unroll
    for (int tt = 0; tt < 12; tt++) {
        int n = tt * 16 + ln;
        #pragma unroll
        for (int r = 0; r < 4; r++) {
            int m = mt * 16 + quad * 4 + r;
            if (m < N) feat_out[(size_t)m * 192 + n] = (_Float16)acc[tt][r];
        }
    }
    #pragma unroll
    for (int tt = 12; tt < 14; tt++) {
        int n32 = (tt - 12) * 16 + ln;
        float bm = (b3[n32] + b3[32 + n32] + b3[64 + n32] + b3[96 + n32] +
                    b3[128 + n32] + b3[160 + n32]) * (1.0f / 6.0f);
        #pragma unroll
        for (int r = 0; r < 4; r++) {
            int m = mt * 16 + quad * 4 + r;
            if (m < N) out[(size_t)m * 32 + n32] = acc[tt][r] + bm;
        }
    }
    #pragma unroll
    for (int hg = 0; hg < H; hg++) {
        float a0 = al[hg * 32 + ln], a1 = al[hg * 32 + 16 + ln];
        float r0 = ar[hg * 32 + ln], r1 = ar[hg * 32 + 16 + ln];
        #pragma unroll
        for (int r = 0; r < 4; r++) {
            float pl = acc[2 * hg][r] * a0 + acc[2 * hg + 1][r] * a1;
            float pr = acc[2 * hg][r] * r0 + acc[2 * hg + 1][r] * r1;
            #pragma unroll
            for (int off = 1; off < 16; off <<= 1) {
                pl += __shfl_xor(pl, off);
                pr += __shfl_xor(pr, off);
            }
            int m = mt * 16 + quad * 4 + r;
            if (ln == 0 && m < N) {
                el8[(size_t)m * 8 + hg] = pl;
                er8[(size_t)m * 8 + hg] = pr;
            }
        }
    }
}

// ---------------- layer-3 edge weights: wexp[j][6] = exp(leaky(el[s]+er[d])) ----------------
// CSR order, reads packed (s,d) in ONE 8B load. el8 gathers hit the 1.6MB L2-resident
// table; er8 reads near-sequential (CSR sorted by dst). Writes coalesced.

__global__ void wexp_l3(const int2* __restrict__ csr_sd,
                        const float* __restrict__ el8, const float* __restrict__ er8,
                        float* __restrict__ wexp, int E) {
    int i = blockIdx.x * blockDim.x + threadIdx.x;
    if (i >= E) return;
    int2 sd = csr_sd[i];
    int s = sd.x, d = sd.y;
    float4 a0 = *(const float4*)(el8 + (size_t)s * 8);
    float2 a1 = *(const float2*)(el8 + (size_t)s * 8 + 4);
    float4 b0 = *(const float4*)(er8 + (size_t)d * 8);
    float2 b1 = *(const float2*)(er8 + (size_t)d * 8 + 4);
    float e[6] = {a0.x + b0.x, a0.y + b0.y, a0.z + b0.z, a0.w + b0.w,
                  a1.x + b1.x, a1.y + b1.y};
    float* wp = wexp + (size_t)i * 6;
    #pragma unroll
    for (int h = 0; h < 6; h++) {
        float v = e[h];
        v = (v >= 0.f) ? v : 0.2f * v;
        wp[h] = __expf(v);
    }
}

// ---------------- layers 1/2 aggregate: QUARTER-WAVE HEAD-SPLIT, XCD-PINNED ----------------
// Block = 256 thr = 4 waves; wave covers 4 (node,head) slices of 16 lanes. Slice lane:
// q = sl&3 (dim quad: dims h*32+8q..+7), g = sl>>2 (edge group 0..3). 4x-unrolled edge
// loop (round 9) -> 16 gathers in flight per slice. Reduce = 2 shuffle stages (xor 4,8).
// Block->task map uses hardware round-robin (blockIdx%8 -> XCD): t=(b&7)*C+(b>>3);
// h=t/NB16 (head-major order => each XCD streams one 3.2MB plane at a time).
// RES: 0 none, 1 packed hi/lo identity residual. Output: relu + packed hi/lo planes.
// All shuffles unconditional; loads clamped, stores guarded.

template <int RES>
__global__ __launch_bounds__(256) void gat_agg_q(
        const _Float16* __restrict__ feat_planes, const float* __restrict__ el,
        const float* __restrict__ er, const int* __restrict__ row_start,
        const int2* __restrict__ csr_sd, const float* __restrict__ bias,
        const _Float16* __restrict__ res_hi, const _Float16* __restrict__ res_lo,
        _Float16* __restrict__ out_hi, _Float16* __restrict__ out_lo,
        int N, int NB16) {
    constexpr int H = 4;
    unsigned b = blockIdx.x;
    unsigned C = (unsigned)(NB16 * H) >> 3;       // blocks per XCD (NB16%2==0 => exact)
    unsigned t = (b & 7u) * C + (b >> 3);
    int h  = (int)(t / (unsigned)NB16);
    int ng = (int)(t - (unsigned)h * (unsigned)NB16);
    int wv = threadIdx.x >> 6, lane = threadIdx.x & 63;
    int slice = lane >> 4, sl = lane & 15;
    int q = sl & 3;          // dim quad
    int g = sl >> 2;         // edge group 0..3
    int n = ng * 16 + wv * 4 + slice;
    bool valid = (n < N);
    int nc = valid ? n : (N - 1);

    int start = row_start[nc];
    int end   = valid ? row_start[nc + 1] : start;
    float er_h = er[(size_t)h * N + nc];
    const float* el_h = el + (size_t)h * N;
    const _Float16* fbase = feat_planes + (size_t)h * N * 32 + q * 8;

    float acc[8];
    #pragma unroll
    for (int i = 0; i < 8; i++) acc[i] = 0.f;
    float wsum = 0.f;

    int j = start + g;
    for (; j + 12 < end; j += 16) {
        int s0 = csr_sd[j].x;
        int s1 = csr_sd[j + 4].x;
        int s2 = csr_sd[j + 8].x;
        int s3 = csr_sd[j + 12].x;
        float e0 = el_h[s0] + er_h;
        float e1 = el_h[s1] + er_h;
        float e2 = el_h[s2] + er_h;
        float e3 = el_h[s3] + er_h;
        e0 = (e0 >= 0.f) ? e0 : 0.2f * e0;
        e1 = (e1 >= 0.f) ? e1 : 0.2f * e1;
        e2 = (e2 >= 0.f) ? e2 : 0.2f * e2;
        e3 = (e3 >= 0.f) ? e3 : 0.2f * e3;
        float w0 = __expf(e0);
        float w1 = __expf(e1);
        float w2 = __expf(e2);
        float w3 = __expf(e3);
        v8h v0 = *(const v8h*)(fbase + (size_t)s0 * 32);
        v8h v1 = *(const v8h*)(fbase + (size_t)s1 * 32);
        v8h v2 = *(const v8h*)(fbase + (size_t)s2 * 32);
        v8h v3 = *(const v8h*)(fbase + (size_t)s3 * 32);
        wsum += (w0 + w1) + (w2 + w3);
        #pragma unroll
        for (int i = 0; i < 8; i++)
            acc[i] += (w0 * (float)v0[i] + w1 * (float)v1[i]) +
                      (w2 * (float)v2[i] + w3 * (float)v3[i]);
    }
    for (; j < end; j += 4) {
        int s0 = csr_sd[j].x;
        float e0 = el_h[s0] + er_h;
        e0 = (e0 >= 0.f) ? e0 : 0.2f * e0;
        float w0 = __expf(e0);
        v8h v0 = *(const v8h*)(fbase + (size_t)s0 * 32);
        wsum += w0;
        #pragma unroll
        for (int i = 0; i < 8; i++) acc[i] += w0 * (float)v0[i];
    }

    // reduce across the 4 edge groups (sl bits 2,3) -- unconditional
    #pragma unroll
    for (int off = 4; off < 16; off <<= 1) {
        #pragma unroll
        for (int i = 0; i < 8; i++) acc[i] += __shfl_xor(acc[i], off);
        wsum += __shfl_xor(wsum, off);
    }

    float inv = 1.0f / fmaxf(wsum, 1e-9f);
    float4 bv0 = *(const float4*)(bias + h * 32 + q * 8);
    float4 bv1 = *(const float4*)(bias + h * 32 + q * 8 + 4);
    float r[8];
    r[0] = acc[0] * inv + bv0.x; r[1] = acc[1] * inv + bv0.y;
    r[2] = acc[2] * inv + bv0.z; r[3] = acc[3] * inv + bv0.w;
    r[4] = acc[4] * inv + bv1.x; r[5] = acc[5] * inv + bv1.y;
    r[6] = acc[6] * inv + bv1.z; r[7] = acc[7] * inv + bv1.w;

    if constexpr (RES == 1) {
        int off = pack_off(nc, h * 32 + q * 8);
        v8h rh = *(const v8h*)(res_hi + off);
        v8h rl = *(const v8h*)(res_lo + off);
        #pragma unroll
        for (int i = 0; i < 8; i++) r[i] += (float)rh[i] + (float)rl[i];
    }
    #pragma unroll
    for (int i = 0; i < 8; i++) r[i] = fmaxf(r[i], 0.f);

    if (g == 0 && valid) {
        int po = pack_off(n, h * 32 + q * 8);
        v8h hh, ll;
        #pragma unroll
        for (int i = 0; i < 8; i++) {
            hh[i] = (_Float16)r[i];
            ll[i] = (_Float16)(r[i] - (float)hh[i]);
        }
        *(v8h*)(out_hi + po) = hh;
        *(v8h*)(out_lo + po) = ll;
    }
}

// ---------------- layer 3 aggregate: precomputed weights, INTERLEAVED gather ----------------
// 24 dim-lanes (lane d8: dims 8*d8..+7 of the 192-dim row; hd = d8>>2), G=2 edge groups,
// 6x-unrolled (round 9: 12 edges in flight/wave, VGPR kept <= 64). Hot loop: csr_sd.x
// (stream) + wexp (stream) + ONE dependent feat gather -- no el load, no exp (round-5
// lesson). fc3 prefilled out with res_mean + mean_h(b3); ADDS mean_h(acc*inv), plain
// stores (NO atomics, round-3 lesson). Shuffles unconditional; stores guarded (lane<4).

__global__ __launch_bounds__(256) void gat_agg_mean6w(
        const _Float16* __restrict__ feat, const float* __restrict__ wexp,
        const int* __restrict__ row_start, const int2* __restrict__ csr_sd,
        float* __restrict__ out, int N) {
    constexpr int H = 6, ROW = 192, LPG = 24, G = 2;
    int wv = threadIdx.x >> 6, lane = threadIdx.x & 63;
    int n = blockIdx.x * 4 + wv;
    if (n >= N) return;

    int d8 = lane % LPG;
    int g  = lane / LPG;      // 0,1 active; 2 idle in gather
    int hd = d8 >> 2, qb = d8 & 3;

    int start = row_start[n], end = row_start[n + 1];
    const _Float16* fbase = feat + 8 * d8;

    float acc[8];
    #pragma unroll
    for (int q = 0; q < 8; q++) acc[q] = 0.f;
    float wsum = 0.f;

    int j = (g < G) ? (start + g) : end;
    for (; j + 5 * G < end; j += 6 * G) {
        int s0 = csr_sd[j].x;
        int s1 = csr_sd[j + G].x;
        int s2 = csr_sd[j + 2 * G].x;
        int s3 = csr_sd[j + 3 * G].x;
        int s4 = csr_sd[j + 4 * G].x;
        int s5 = csr_sd[j + 5 * G].x;
        float w0 = wexp[(size_t)j * 6 + hd];
        float w1 = wexp[(size_t)(j + G) * 6 + hd];
        float w2 = wexp[(size_t)(j + 2 * G) * 6 + hd];
        float w3 = wexp[(size_t)(j + 3 * G) * 6 + hd];
        float w4 = wexp[(size_t)(j + 4 * G) * 6 + hd];
        float w5 = wexp[(size_t)(j + 5 * G) * 6 + hd];
        v8h v0 = *(const v8h*)(fbase + (size_t)s0 * ROW);
        v8h v1 = *(const v8h*)(fbase + (size_t)s1 * ROW);
        v8h v2 = *(const v8h*)(fbase + (size_t)s2 * ROW);
        v8h v3 = *(const v8h*)(fbase + (size_t)s3 * ROW);
        v8h v4 = *(const v8h*)(fbase + (size_t)s4 * ROW);
        v8h v5 = *(const v8h*)(fbase + (size_t)s5 * ROW);
        wsum += ((w0 + w1) + (w2 + w3)) + (w4 + w5);
        #pragma unroll
        for (int q = 0; q < 8; q++)
            acc[q] += ((w0 * (float)v0[q] + w1 * (float)v1[q]) +
                       (w2 * (float)v2[q] + w3 * (float)v3[q])) +
                      (w4 * (float)v4[q] + w5 * (float)v5[q]);
    }
    for (; j < end; j += G) {
        int s0 = csr_sd[j].x;
        float w0 = wexp[(size_t)j * 6 + hd];
        v8h v0 = *(const v8h*)(fbase + (size_t)s0 * ROW);
        wsum += w0;
        #pragma unroll
        for (int q = 0; q < 8; q++) acc[q] += w0 * (float)v0[q];
    }

    // cross-group combine (G == 2, LPG == 24: partner lane +24), unconditional
    #pragma unroll
    for (int q = 0; q < 8; q++) acc[q] += __shfl(acc[q], lane + 24);
    wsum += __shfl(wsum, lane + 24);

    float inv = 1.0f / fmaxf(wsum, 1e-9f);
    float r[8];
    #pragma unroll
    for (int q = 0; q < 8; q++) r[q] = acc[q] * inv;

    // head-mean: lane d8 = hd*4 + qb; sum over heads from lanes qb+4*hh, unconditional
    float s[8];
    #pragma unroll
    for (int q = 0; q < 8; q++) {
        s[q] = r[q];
        #pragma unroll
        for (int hh2 = 1; hh2 < H; hh2++) s[q] += __shfl(r[q], qb + 4 * hh2);
    }
    if (lane < 4) {
        const float sc = 1.0f / 6.0f;
        float4 rm0 = *(const float4*)(out + (size_t)n * 32 + 8 * lane);
        float4 rm1 = *(const float4*)(out + (size_t)n * 32 + 8 * lane + 4);
        *(float4*)(out + (size_t)n * 32 + 8 * lane) =
            make_float4(s[0] * sc + rm0.x, s[1] * sc + rm0.y,
                        s[2] * sc + rm0.z, s[3] * sc + rm0.w);
        *(float4*)(out + (size_t)n * 32 + 8 * lane + 4) =
            make_float4(s[4] * sc + rm1.x, s[5] * sc + rm1.y,
                        s[6] * sc + rm1.z, s[7] * sc + rm1.w);
    }
}

// ---------------- launch ----------------

extern "C" void kernel_launch(void* const* d_in, const int* in_sizes, int n_in,
                              void* d_out, int out_size, void* d_ws, size_t ws_size,
                              hipStream_t stream) {
    const float* x    = (const float*)d_in[0];
    const int*   src  = (const int*)d_in[1];
    const int*   dst  = (const int*)d_in[2];
    const float* W1   = (const float*)d_in[3];
    const float* al1  = (const float*)d_in[4];
    const float* ar1  = (const float*)d_in[5];
    const float* b1   = (const float*)d_in[6];
    const float* W2   = (const float*)d_in[7];
    const float* al2  = (const float*)d_in[8];
    const float* ar2  = (const float*)d_in[9];
    const float* b2   = (const float*)d_in[10];
    const float* W3   = (const float*)d_in[11];
    const float* al3  = (const float*)d_in[12];
    const float* ar3  = (const float*)d_in[13];
    const float* b3   = (const float*)d_in[14];
    const float* resW3= (const float*)d_in[15];
    float* out = (float*)d_out;

    const int N = in_sizes[0] / 128;
    const int E = in_sizes[1];
    const int TILES16 = (N + 15) / 16;
    const int PT = (TILES16 + 3) & ~3;
    const int NB = PT / 4;
    const int NSB = (N + 2047) / 2048;     // scan blocks
    const int NB16 = (TILES16 + 3) & ~3;   // 16-node groups, mult of 4 (XCD map exact)

    // workspace layout (8/16B alignment: csr_sd and el8/er8 placed before odd-sized int arrays)
    float* fws  = (float*)d_ws;
    float* elb  = fws;                           // [6][N] planes (L1/L2)
    float* erb  = elb + (size_t)N * 6;           // [6][N]
    _Float16* feat_h = (_Float16*)(erb + (size_t)N * 6);  // L1/2: [4][N][32] planes; L3: [N][192]
    _Float16* xh_hi  = feat_h + (size_t)N * 192;          // PT*2048 (x packed; reused as h2)
    _Float16* xh_lo  = xh_hi + (size_t)PT * 2048;
    _Float16* h1_hi  = xh_lo + (size_t)PT * 2048;         // h1 planes; dead after L2 agg ->
    _Float16* h1_lo  = h1_hi + (size_t)PT * 2048;         //   reused as wexp[E][6] f32
    _Float16* wts    = h1_lo + (size_t)PT * 2048;         // 122880 f16
    int2* csr_sd   = (int2*)(wts + 122880);      // [E] packed (src,dst)
    float* el8     = (float*)(csr_sd + E);       // [N][8] padded logit tables (L3)
    float* er8     = el8 + (size_t)N * 8;
    int* deg       = (int*)(er8 + (size_t)N * 8);
    int* row_start = deg + N;
    int* bsum      = row_start + (N + 1);
    int* rank      = bsum + 64;                  // [E] per-edge in-bucket rank
    float* wexp    = (float*)h1_hi;              // [E][6] f32, overlays dead h1 planes

    const _Float16* W1h = wts;
    const _Float16* W1l = wts + 16384;
    const _Float16* W2h = wts + 32768;
    const _Float16* W2l = wts + 49152;
    const _Float16* B3h = wts + 65536;          // [W3 12 tiles | resm 2 tiles]
    const _Float16* B3l = wts + 94208;

    // ---- CSR build (by dst): ONE returning-atomic pass + scan + atomic-free fill ----
    hipMemsetAsync(deg, 0, (size_t)N * sizeof(int), stream);
    hist_rank<<<dim3((E + 255) / 256), dim3(256), 0, stream>>>(dst, E, deg, rank);
    scan_phaseA<<<dim3(NSB), dim3(256), 0, stream>>>(deg, N, bsum);
    scan_phaseB<<<dim3(1), dim3(64), 0, stream>>>(bsum, NSB);
    scan_phaseC<<<dim3(NSB), dim3(256), 0, stream>>>(deg, N, bsum, row_start, E);
    fill_kernel<<<dim3((E + 255) / 256), dim3(256), 0, stream>>>(src, dst, E, row_start, rank, csr_sd);
    wsplit_all<<<dim3(240), dim3(256), 0, stream>>>(W1, W2, W3, resW3, wts);
    splitx_kernel<<<dim3((PT * 2048 + 255) / 256), dim3(256), 0, stream>>>(x, xh_hi, xh_lo, N, PT);

    // ---- Layer 1 ----
    mfma_fc<128, 4><<<dim3(NB), dim3(256), 0, stream>>>(
        xh_hi, xh_lo, W1h, W1l, al1, ar1, feat_h, elb, erb, N);
    gat_agg_q<0><<<dim3(NB16 * 4), dim3(256), 0, stream>>>(
        feat_h, elb, erb, row_start, csr_sd, b1,
        nullptr, nullptr, h1_hi, h1_lo, N, NB16);

    // ---- Layer 2 (identity residual = h1 packed planes) ----
    mfma_fc<128, 4><<<dim3(NB), dim3(256), 0, stream>>>(
        h1_hi, h1_lo, W2h, W2l, al2, ar2, feat_h, elb, erb, N);
    gat_agg_q<1><<<dim3(NB16 * 4), dim3(256), 0, stream>>>(
        feat_h, elb, erb, row_start, csr_sd, b2,
        h1_hi, h1_lo, xh_hi, xh_lo, N, NB16);   // h2 -> reuse x planes

    // ---- Layer 3: GEMM (feat + logit tables + res/bias mean -> out), wexp, mean-agg ----
    mfma_fc3<<<dim3(NB), dim3(256), 0, stream>>>(
        xh_hi, xh_lo, B3h, B3l, al3, ar3, b3, feat_h, out, el8, er8, N);
    wexp_l3<<<dim3((E + 255) / 256), dim3(256), 0, stream>>>(
        csr_sd, el8, er8, wexp, E);
    gat_agg_mean6w<<<dim3((N + 3) / 4), dim3(256), 0, stream>>>(
        feat_h, wexp, row_start, csr_sd, out, N);
}

// Round 10
// 397.626 us; speedup vs baseline: 1.0491x; 1.0491x over previous
//
#include <hip/hip_runtime.h>
#include <math.h>

// GAT 3-layer forward on MI355X.
// N=50000 nodes, E=850000 edges (incl self loops), IN=128, HID=OUT=32, HEADS=(4,4,6).
// GEMMs: split-f16 MFMA (hi/lo, 3 mfma), LDS-free; A and B pre-packed in MFMA-fragment
// order (pack_off) -> every wave load is 1KB contiguous. NEVER partial-unroll the tile
// loop (dynamic acc[] indexing -> scratch spill, round 4).
// Layer-3 residual+bias folded THROUGH the head-mean: resm = mean_h(resW3 slices) is 2
// extra B-tiles in mfma_fc3; fc3 writes res_m + mean_h(b3) DIRECTLY into d_out (full
// overwrite -> replay-idempotent); layer-3 agg ADDS the softmax mean (plain stores).
// ROUND-3 LESSON: NEVER use global fp32 atomicAdd for the head-mean (300MB WRITE, 4.5x).
// ROUND-4 LESSON: layer-3 gather must be INTERLEAVED [N][192]; head planes only pay
// when the per-XCD working set is L2-resident (L1/L2 agg).
// ROUND-5 LESSON: gather limiter = INDEPENDENT requests in flight; dependent chains
// (csr->el->exp->feat) throttle issue. wexp[E][6] precompute fixed layer-3 agg.
// ROUND-6/7/8 LESSON: returning-atomic sweep is parallelism-bound; do the returning
// atomic ONCE (hist_rank keeps the return as in-bucket rank), fill is then ZERO-atomic
// (row_start[d]+rank[i], int2 packed scatter). Round 8: 446->404us.
// ROUND-9 LESSON: unroll deeper than 4x REGRESSES (54.6->69.4us, BW 2.92->2.30TB/s):
// at avg degree 17 (~8.5 edges/lane-group) the 6x main loop runs once and pushes the
// rest into the 1-deep serial tail -- in-flight gathers DROP. 4x is the sweet spot;
// per-wave MLP is exhausted. This file = round-8 config + 2x-step mid-tail in mean6w.
// Aggregation L1/L2: QUARTER-WAVE head-split (16 lanes/(node,head), 4 lanes/edge, G=4),
// feat head planes [H][N][32] f16 + el/er planes [H][N], XCD-pinned (blockIdx%8 -> XCD,
// head-major order) -> compulsory fetch. Round-1 lesson: 1 wave/(node,head) = 4x waves
// = overhead-bound. All cross-lane shuffles execute unconditionally; stores guarded.
// CSR prefix scan: 3-phase multi-block.

typedef _Float16 v8h __attribute__((ext_vector_type(8)));
typedef float f32x4 __attribute__((ext_vector_type(4)));

// packed fragment offset for row n, k-dim k (128-wide K):
__device__ __host__ inline int pack_off(int n, int k) {
    return ((n >> 4) << 11) | ((k >> 5) << 9) | (((k >> 3) & 3) << 7) | ((n & 15) << 3) | (k & 7);
}

// ---------------- CSR build (by dst) ----------------

// ONE returning-atomic pass: deg histogram AND per-edge in-bucket rank.
__global__ void hist_rank(const int* __restrict__ dst, int E,
                          int* __restrict__ deg, int* __restrict__ rank) {
    int i = blockIdx.x * blockDim.x + threadIdx.x;
    if (i < E) rank[i] = atomicAdd(&deg[dst[i]], 1);
}

__global__ void scan_phaseA(const int* __restrict__ deg, int n, int* __restrict__ bsum) {
    __shared__ int red[4];
    int t = threadIdx.x;
    int base = blockIdx.x * 2048 + t * 8;
    int s = 0;
    #pragma unroll
    for (int q = 0; q < 8; q++) { int i = base + q; if (i < n) s += deg[i]; }
    #pragma unroll
    for (int off = 1; off < 64; off <<= 1) s += __shfl_xor(s, off);
    if ((t & 63) == 0) red[t >> 6] = s;
    __syncthreads();
    if (t == 0) bsum[blockIdx.x] = red[0] + red[1] + red[2] + red[3];
}

__global__ void scan_phaseB(int* __restrict__ bsum, int nb) {
    int lane = threadIdx.x & 63;
    int v = (lane < nb) ? bsum[lane] : 0;
    int inc = v;
    #pragma unroll
    for (int off = 1; off < 64; off <<= 1) {
        int u = __shfl_up(inc, off);
        if (lane >= off) inc += u;
    }
    int ex = inc - v;
    if (lane < nb) bsum[lane] = ex;
}

__global__ void scan_phaseC(const int* __restrict__ deg, int n, const int* __restrict__ bsum,
                            int* __restrict__ row_start, int E) {
    __shared__ int wsum[4];
    int t = threadIdx.x;
    int lane = t & 63, wv = t >> 6;
    int base = blockIdx.x * 2048 + t * 8;
    int v[8]; int s = 0;
    #pragma unroll
    for (int q = 0; q < 8; q++) { int i = base + q; v[q] = (i < n) ? deg[i] : 0; s += v[q]; }
    int inc = s;
    #pragma unroll
    for (int off = 1; off < 64; off <<= 1) {
        int u = __shfl_up(inc, off);
        if (lane >= off) inc += u;
    }
    if (lane == 63) wsum[wv] = inc;
    __syncthreads();
    int woff = 0;
    for (int w = 0; w < wv; w++) woff += wsum[w];
    int run = inc - s + woff + bsum[blockIdx.x];
    #pragma unroll
    for (int q = 0; q < 8; q++) {
        int i = base + q;
        if (i < n) row_start[i] = run;
        run += v[q];
    }
    if (blockIdx.x == 0 && t == 0) row_start[n] = E;
}

// ZERO-atomic fill: position = row_start[d] (L2-resident gather) + rank[i] (stream).
// Single packed int2 scattered store (1 random 64B sector per edge).
__global__ void fill_kernel(const int* __restrict__ src, const int* __restrict__ dst, int E,
                            const int* __restrict__ row_start, const int* __restrict__ rank,
                            int2* __restrict__ csr_sd) {
    int i = blockIdx.x * blockDim.x + threadIdx.x;
    if (i < E) {
        int s = src[i], d = dst[i];
        int at = row_start[d] + rank[i];
        csr_sd[at] = make_int2(s, d);
    }
}

// ---------------- weight hi/lo split into PACKED fragment layout ----------------
// Regions: W1 (128c x 128k), W2 (128c x 128k), B3 = [W3 192c | resm 32c] x 128k.
// resm[k][c] = mean over 6 heads of resW3[k][h*32+c]  (residual folded through head-mean).

__global__ void wsplit_all(const float* __restrict__ W1, const float* __restrict__ W2,
                           const float* __restrict__ W3, const float* __restrict__ Wr,
                           _Float16* __restrict__ o) {
    int i = blockIdx.x * blockDim.x + threadIdx.x;
    if (i >= 61440) return;
    float v; int ohi, stride, po;
    if (i < 16384) {
        int e = i, c = e >> 7, k = e & 127;
        v = W1[(size_t)k * 128 + c]; ohi = 0; stride = 16384; po = pack_off(c, k);
    } else if (i < 32768) {
        int e = i - 16384, c = e >> 7, k = e & 127;
        v = W2[(size_t)k * 128 + c]; ohi = 32768; stride = 16384; po = pack_off(c, k);
    } else if (i < 57344) {
        int e = i - 32768, c = e >> 7, k = e & 127;
        v = W3[(size_t)k * 192 + c]; ohi = 65536; stride = 28672; po = pack_off(c, k);
    } else {
        int e = i - 57344, c = e >> 7, k = e & 127;
        float s = 0.f;
        #pragma unroll
        for (int h = 0; h < 6; h++) s += Wr[(size_t)k * 192 + h * 32 + c];
        v = s * (1.0f / 6.0f);
        ohi = 65536; stride = 28672; po = 24576 + pack_off(c, k);
    }
    _Float16 hv = (_Float16)v;
    o[ohi + po] = hv;
    o[ohi + stride + po] = (_Float16)(v - (float)hv);
}

// ---------------- x -> packed hi/lo f16 fragment layout ----------------

__global__ void splitx_kernel(const float* __restrict__ x, _Float16* __restrict__ hi,
                              _Float16* __restrict__ lo, int N, int PT) {
    int i = blockIdx.x * blockDim.x + threadIdx.x;
    if (i >= PT * 2048) return;
    int mt = i >> 11, r = i & 2047;
    int q4 = r >> 9, quad = (r >> 7) & 3, ln = (r >> 3) & 15, j = r & 7;
    int n = mt * 16 + ln, k = q4 * 32 + quad * 8 + j;
    float v = (n < N) ? x[(size_t)n * 128 + k] : 0.f;
    _Float16 h = (_Float16)v;
    hi[i] = h;
    lo[i] = (_Float16)(v - (float)h);
}

// ---------------- LDS-free MFMA fc (+ attention logits), layers 1/2 ----------------
// feat_out is HEAD-MAJOR PLANES: [H][N][32] f16; el/er are planes [H][N].

template <int CC, int H>
__global__ __launch_bounds__(256, 4) void mfma_fc(
    const _Float16* __restrict__ Ahi, const _Float16* __restrict__ Alo,
    const _Float16* __restrict__ Bhi, const _Float16* __restrict__ Blo,
    const float* __restrict__ al, const float* __restrict__ ar,
    _Float16* __restrict__ feat_out,
    float* __restrict__ el, float* __restrict__ er, int N) {
    constexpr int TILES = CC / 16;
    int t = threadIdx.x;
    int wave = t >> 6, lane = t & 63;
    int ln = lane & 15, quad = lane >> 4;
    int mt = blockIdx.x * 4 + wave;

    f32x4 acc[TILES];
    #pragma unroll
    for (int i = 0; i < TILES; i++) acc[i] = (f32x4){0.f, 0.f, 0.f, 0.f};

    const _Float16* pa_h = Ahi + (size_t)mt * 2048 + lane * 8;
    const _Float16* pa_l = Alo + (size_t)mt * 2048 + lane * 8;

    #pragma unroll
    for (int q4 = 0; q4 < 4; q4++) {
        v8h ah = *(const v8h*)(pa_h + q4 * 512);
        v8h av = *(const v8h*)(pa_l + q4 * 512);
        #pragma unroll
        for (int tt = 0; tt < TILES; tt++) {
            size_t boff = (size_t)tt * 2048 + q4 * 512 + lane * 8;
            v8h bh = *(const v8h*)(Bhi + boff);
            v8h bl = *(const v8h*)(Blo + boff);
            acc[tt] = __builtin_amdgcn_mfma_f32_16x16x32_f16(av, bh, acc[tt], 0, 0, 0);
            acc[tt] = __builtin_amdgcn_mfma_f32_16x16x32_f16(ah, bl, acc[tt], 0, 0, 0);
            acc[tt] = __builtin_amdgcn_mfma_f32_16x16x32_f16(ah, bh, acc[tt], 0, 0, 0);
        }
    }

    #pragma unroll
    for (int tt = 0; tt < TILES; tt++) {
        int n = tt * 16 + ln;
        int head = n >> 5, wi = n & 31;
        _Float16* fo = feat_out + (size_t)head * N * 32;
        #pragma unroll
        for (int r = 0; r < 4; r++) {
            int m = mt * 16 + quad * 4 + r;
            if (m < N) fo[(size_t)m * 32 + wi] = (_Float16)acc[tt][r];
        }
    }
    #pragma unroll
    for (int hg = 0; hg < H; hg++) {
        float a0 = al[hg * 32 + ln], a1 = al[hg * 32 + 16 + ln];
        float r0 = ar[hg * 32 + ln], r1 = ar[hg * 32 + 16 + ln];
        #pragma unroll
        for (int r = 0; r < 4; r++) {
            float pl = acc[2 * hg][r] * a0 + acc[2 * hg + 1][r] * a1;
            float pr = acc[2 * hg][r] * r0 + acc[2 * hg + 1][r] * r1;
            #pragma unroll
            for (int off = 1; off < 16; off <<= 1) {
                pl += __shfl_xor(pl, off);
                pr += __shfl_xor(pr, off);
            }
            int m = mt * 16 + quad * 4 + r;
            if (ln == 0 && m < N) {
                el[(size_t)hg * N + m] = pl;
                er[(size_t)hg * N + m] = pr;
            }
        }
    }
}

// ---------------- layer 3: single pass, 14 tiles ----------------
// Tiles 0..11 = W3 feat -> INTERLEAVED [N][192] f16 (round-4 lesson). Tiles 12..13 =
// res-mean fp32, written (+ mean_h(b3)) DIRECTLY into d_out; agg then ADDS softmax mean.
// Logits go to PADDED [N][8] tables el8/er8 (32B rows, L2-resident for wexp_l3).

__global__ __launch_bounds__(256, 3) void mfma_fc3(
    const _Float16* __restrict__ Ahi, const _Float16* __restrict__ Alo,
    const _Float16* __restrict__ Bhi, const _Float16* __restrict__ Blo,
    const float* __restrict__ al, const float* __restrict__ ar,
    const float* __restrict__ b3,
    _Float16* __restrict__ feat_out, float* __restrict__ out,
    float* __restrict__ el8, float* __restrict__ er8, int N) {
    constexpr int H = 6, TILES = 14;
    int t = threadIdx.x;
    int wave = t >> 6, lane = t & 63;
    int ln = lane & 15, quad = lane >> 4;
    int mt = blockIdx.x * 4 + wave;

    f32x4 acc[TILES];
    #pragma unroll
    for (int i = 0; i < TILES; i++) acc[i] = (f32x4){0.f, 0.f, 0.f, 0.f};

    const _Float16* pa_h = Ahi + (size_t)mt * 2048 + lane * 8;
    const _Float16* pa_l = Alo + (size_t)mt * 2048 + lane * 8;

    #pragma unroll
    for (int q4 = 0; q4 < 4; q4++) {
        v8h ah = *(const v8h*)(pa_h + q4 * 512);
        v8h av = *(const v8h*)(pa_l + q4 * 512);
        #pragma unroll
        for (int tt = 0; tt < TILES; tt++) {
            size_t boff = (size_t)tt * 2048 + q4 * 512 + lane * 8;
            v8h bh = *(const v8h*)(Bhi + boff);
            v8h bl = *(const v8h*)(Blo + boff);
            acc[tt] = __builtin_amdgcn_mfma_f32_16x16x32_f16(av, bh, acc[tt], 0, 0, 0);
            acc[tt] = __builtin_amdgcn_mfma_f32_16x16x32_f16(ah, bl, acc[tt], 0, 0, 0);
            acc[tt] = __builtin_amdgcn_mfma_f32_16x16x32_f16(ah, bh, acc[tt], 0, 0, 0);
        }
    }

    #pragma unroll
    for (int tt = 0; tt < 12; tt++) {
        int n = tt * 16 + ln;
        #pragma unroll
        for (int r = 0; r < 4; r++) {
            int m = mt * 16 + quad * 4 + r;
            if (m < N) feat_out[(size_t)m * 192 + n] = (_Float16)acc[tt][r];
        }
    }
    #pragma unroll
    for (int tt = 12; tt < 14; tt++) {
        int n32 = (tt - 12) * 16 + ln;
        float bm = (b3[n32] + b3[32 + n32] + b3[64 + n32] + b3[96 + n32] +
                    b3[128 + n32] + b3[160 + n32]) * (1.0f / 6.0f);
        #pragma unroll
        for (int r = 0; r < 4; r++) {
            int m = mt * 16 + quad * 4 + r;
            if (m < N) out[(size_t)m * 32 + n32] = acc[tt][r] + bm;
        }
    }
    #pragma unroll
    for (int hg = 0; hg < H; hg++) {
        float a0 = al[hg * 32 + ln], a1 = al[hg * 32 + 16 + ln];
        float r0 = ar[hg * 32 + ln], r1 = ar[hg * 32 + 16 + ln];
        #pragma unroll
        for (int r = 0; r < 4; r++) {
            float pl = acc[2 * hg][r] * a0 + acc[2 * hg + 1][r] * a1;
            float pr = acc[2 * hg][r] * r0 + acc[2 * hg + 1][r] * r1;
            #pragma unroll
            for (int off = 1; off < 16; off <<= 1) {
                pl += __shfl_xor(pl, off);
                pr += __shfl_xor(pr, off);
            }
            int m = mt * 16 + quad * 4 + r;
            if (ln == 0 && m < N) {
                el8[(size_t)m * 8 + hg] = pl;
                er8[(size_t)m * 8 + hg] = pr;
            }
        }
    }
}

// ---------------- layer-3 edge weights: wexp[j][6] = exp(leaky(el[s]+er[d])) ----------------
// CSR order, reads packed (s,d) in ONE 8B load. el8 gathers hit the 1.6MB L2-resident
// table; er8 reads near-sequential (CSR sorted by dst). Writes coalesced.

__global__ void wexp_l3(const int2* __restrict__ csr_sd,
                        const float* __restrict__ el8, const float* __restrict__ er8,
                        float* __restrict__ wexp, int E) {
    int i = blockIdx.x * blockDim.x + threadIdx.x;
    if (i >= E) return;
    int2 sd = csr_sd[i];
    int s = sd.x, d = sd.y;
    float4 a0 = *(const float4*)(el8 + (size_t)s * 8);
    float2 a1 = *(const float2*)(el8 + (size_t)s * 8 + 4);
    float4 b0 = *(const float4*)(er8 + (size_t)d * 8);
    float2 b1 = *(const float2*)(er8 + (size_t)d * 8 + 4);
    float e[6] = {a0.x + b0.x, a0.y + b0.y, a0.z + b0.z, a0.w + b0.w,
                  a1.x + b1.x, a1.y + b1.y};
    float* wp = wexp + (size_t)i * 6;
    #pragma unroll
    for (int h = 0; h < 6; h++) {
        float v = e[h];
        v = (v >= 0.f) ? v : 0.2f * v;
        wp[h] = __expf(v);
    }
}

// ---------------- layers 1/2 aggregate: QUARTER-WAVE HEAD-SPLIT, XCD-PINNED ----------------
// Block = 256 thr = 4 waves; wave covers 4 (node,head) slices of 16 lanes. Slice lane:
// q = sl&3 (dim quad: dims h*32+8q..+7), g = sl>>2 (edge group 0..3). 2x-unrolled edge
// loop (round-8 proven; deeper regresses at avg deg 17). Reduce = 2 shuffle stages.
// Block->task map uses hardware round-robin (blockIdx%8 -> XCD): t=(b&7)*C+(b>>3);
// h=t/NB16 (head-major order => each XCD streams one 3.2MB plane at a time).
// RES: 0 none, 1 packed hi/lo identity residual. Output: relu + packed hi/lo planes.
// All shuffles unconditional; loads clamped, stores guarded.

template <int RES>
__global__ __launch_bounds__(256) void gat_agg_q(
        const _Float16* __restrict__ feat_planes, const float* __restrict__ el,
        const float* __restrict__ er, const int* __restrict__ row_start,
        const int2* __restrict__ csr_sd, const float* __restrict__ bias,
        const _Float16* __restrict__ res_hi, const _Float16* __restrict__ res_lo,
        _Float16* __restrict__ out_hi, _Float16* __restrict__ out_lo,
        int N, int NB16) {
    constexpr int H = 4;
    unsigned b = blockIdx.x;
    unsigned C = (unsigned)(NB16 * H) >> 3;       // blocks per XCD (NB16%2==0 => exact)
    unsigned t = (b & 7u) * C + (b >> 3);
    int h  = (int)(t / (unsigned)NB16);
    int ng = (int)(t - (unsigned)h * (unsigned)NB16);
    int wv = threadIdx.x >> 6, lane = threadIdx.x & 63;
    int slice = lane >> 4, sl = lane & 15;
    int q = sl & 3;          // dim quad
    int g = sl >> 2;         // edge group 0..3
    int n = ng * 16 + wv * 4 + slice;
    bool valid = (n < N);
    int nc = valid ? n : (N - 1);

    int start = row_start[nc];
    int end   = valid ? row_start[nc + 1] : start;
    float er_h = er[(size_t)h * N + nc];
    const float* el_h = el + (size_t)h * N;
    const _Float16* fbase = feat_planes + (size_t)h * N * 32 + q * 8;

    float acc[8];
    #pragma unroll
    for (int i = 0; i < 8; i++) acc[i] = 0.f;
    float wsum = 0.f;

    int j = start + g;
    for (; j + 4 < end; j += 8) {
        int s0 = csr_sd[j].x;
        int s1 = csr_sd[j + 4].x;
        float e0 = el_h[s0] + er_h;
        float e1 = el_h[s1] + er_h;
        e0 = (e0 >= 0.f) ? e0 : 0.2f * e0;
        e1 = (e1 >= 0.f) ? e1 : 0.2f * e1;
        float w0 = __expf(e0);
        float w1 = __expf(e1);
        v8h v0 = *(const v8h*)(fbase + (size_t)s0 * 32);
        v8h v1 = *(const v8h*)(fbase + (size_t)s1 * 32);
        wsum += w0 + w1;
        #pragma unroll
        for (int i = 0; i < 8; i++) acc[i] += w0 * (float)v0[i] + w1 * (float)v1[i];
    }
    if (j < end) {
        int s0 = csr_sd[j].x;
        float e0 = el_h[s0] + er_h;
        e0 = (e0 >= 0.f) ? e0 : 0.2f * e0;
        float w0 = __expf(e0);
        v8h v0 = *(const v8h*)(fbase + (size_t)s0 * 32);
        wsum += w0;
        #pragma unroll
        for (int i = 0; i < 8; i++) acc[i] += w0 * (float)v0[i];
    }

    // reduce across the 4 edge groups (sl bits 2,3) -- unconditional
    #pragma unroll
    for (int off = 4; off < 16; off <<= 1) {
        #pragma unroll
        for (int i = 0; i < 8; i++) acc[i] += __shfl_xor(acc[i], off);
        wsum += __shfl_xor(wsum, off);
    }

    float inv = 1.0f / fmaxf(wsum, 1e-9f);
    float4 bv0 = *(const float4*)(bias + h * 32 + q * 8);
    float4 bv1 = *(const float4*)(bias + h * 32 + q * 8 + 4);
    float r[8];
    r[0] = acc[0] * inv + bv0.x; r[1] = acc[1] * inv + bv0.y;
    r[2] = acc[2] * inv + bv0.z; r[3] = acc[3] * inv + bv0.w;
    r[4] = acc[4] * inv + bv1.x; r[5] = acc[5] * inv + bv1.y;
    r[6] = acc[6] * inv + bv1.z; r[7] = acc[7] * inv + bv1.w;

    if constexpr (RES == 1) {
        int off = pack_off(nc, h * 32 + q * 8);
        v8h rh = *(const v8h*)(res_hi + off);
        v8h rl = *(const v8h*)(res_lo + off);
        #pragma unroll
        for (int i = 0; i < 8; i++) r[i] += (float)rh[i] + (float)rl[i];
    }
    #pragma unroll
    for (int i = 0; i < 8; i++) r[i] = fmaxf(r[i], 0.f);

    if (g == 0 && valid) {
        int po = pack_off(n, h * 32 + q * 8);
        v8h hh, ll;
        #pragma unroll
        for (int i = 0; i < 8; i++) {
            hh[i] = (_Float16)r[i];
            ll[i] = (_Float16)(r[i] - (float)hh[i]);
        }
        *(v8h*)(out_hi + po) = hh;
        *(v8h*)(out_lo + po) = ll;
    }
}

// ---------------- layer 3 aggregate: precomputed weights, INTERLEAVED gather ----------------
// 24 dim-lanes (lane d8: dims 8*d8..+7 of the 192-dim row; hd = d8>>2), G=2 edge groups,
// 4x-unrolled main + 2x mid-tail + 1x tail (round-9 lesson: 6x regressed -- tail
// dominated at avg deg 17; 4x is the sweet spot). Hot loop: csr_sd.x (stream) + wexp
// (stream) + ONE dependent feat gather -- no el load, no exp (round-5 lesson). fc3
// prefilled out with res_mean + mean_h(b3); ADDS mean_h(acc*inv), plain stores (NO
// atomics, round-3 lesson). Shuffles unconditional; stores guarded (lane<4).

__global__ __launch_bounds__(256) void gat_agg_mean6w(
        const _Float16* __restrict__ feat, const float* __restrict__ wexp,
        const int* __restrict__ row_start, const int2* __restrict__ csr_sd,
        float* __restrict__ out, int N) {
    constexpr int H = 6, ROW = 192, LPG = 24, G = 2;
    int wv = threadIdx.x >> 6, lane = threadIdx.x & 63;
    int n = blockIdx.x * 4 + wv;
    if (n >= N) return;

    int d8 = lane % LPG;
    int g  = lane / LPG;      // 0,1 active; 2 idle in gather
    int hd = d8 >> 2, qb = d8 & 3;

    int start = row_start[n], end = row_start[n + 1];
    const _Float16* fbase = feat + 8 * d8;

    float acc[8];
    #pragma unroll
    for (int q = 0; q < 8; q++) acc[q] = 0.f;
    float wsum = 0.f;

    int j = (g < G) ? (start + g) : end;
    for (; j + 3 * G < end; j += 4 * G) {
        int s0 = csr_sd[j].x;
        int s1 = csr_sd[j + G].x;
        int s2 = csr_sd[j + 2 * G].x;
        int s3 = csr_sd[j + 3 * G].x;
        float w0 = wexp[(size_t)j * 6 + hd];
        float w1 = wexp[(size_t)(j + G) * 6 + hd];
        float w2 = wexp[(size_t)(j + 2 * G) * 6 + hd];
        float w3 = wexp[(size_t)(j + 3 * G) * 6 + hd];
        v8h v0 = *(const v8h*)(fbase + (size_t)s0 * ROW);
        v8h v1 = *(const v8h*)(fbase + (size_t)s1 * ROW);
        v8h v2 = *(const v8h*)(fbase + (size_t)s2 * ROW);
        v8h v3 = *(const v8h*)(fbase + (size_t)s3 * ROW);
        wsum += (w0 + w1) + (w2 + w3);
        #pragma unroll
        for (int q = 0; q < 8; q++)
            acc[q] += (w0 * (float)v0[q] + w1 * (float)v1[q]) +
                      (w2 * (float)v2[q] + w3 * (float)v3[q]);
    }
    // 2x mid-tail: keeps 2 gathers in flight for the first part of the remainder
    for (; j + G < end; j += 2 * G) {
        int s0 = csr_sd[j].x;
        int s1 = csr_sd[j + G].x;
        float w0 = wexp[(size_t)j * 6 + hd];
        float w1 = wexp[(size_t)(j + G) * 6 + hd];
        v8h v0 = *(const v8h*)(fbase + (size_t)s0 * ROW);
        v8h v1 = *(const v8h*)(fbase + (size_t)s1 * ROW);
        wsum += w0 + w1;
        #pragma unroll
        for (int q = 0; q < 8; q++)
            acc[q] += w0 * (float)v0[q] + w1 * (float)v1[q];
    }
    if (j < end) {
        int s0 = csr_sd[j].x;
        float w0 = wexp[(size_t)j * 6 + hd];
        v8h v0 = *(const v8h*)(fbase + (size_t)s0 * ROW);
        wsum += w0;
        #pragma unroll
        for (int q = 0; q < 8; q++) acc[q] += w0 * (float)v0[q];
    }

    // cross-group combine (G == 2, LPG == 24: partner lane +24), unconditional
    #pragma unroll
    for (int q = 0; q < 8; q++) acc[q] += __shfl(acc[q], lane + 24);
    wsum += __shfl(wsum, lane + 24);

    float inv = 1.0f / fmaxf(wsum, 1e-9f);
    float r[8];
    #pragma unroll
    for (int q = 0; q < 8; q++) r[q] = acc[q] * inv;

    // head-mean: lane d8 = hd*4 + qb; sum over heads from lanes qb+4*hh, unconditional
    float s[8];
    #pragma unroll
    for (int q = 0; q < 8; q++) {
        s[q] = r[q];
        #pragma unroll
        for (int hh2 = 1; hh2 < H; hh2++) s[q] += __shfl(r[q], qb + 4 * hh2);
    }
    if (lane < 4) {
        const float sc = 1.0f / 6.0f;
        float4 rm0 = *(const float4*)(out + (size_t)n * 32 + 8 * lane);
        float4 rm1 = *(const float4*)(out + (size_t)n * 32 + 8 * lane + 4);
        *(float4*)(out + (size_t)n * 32 + 8 * lane) =
            make_float4(s[0] * sc + rm0.x, s[1] * sc + rm0.y,
                        s[2] * sc + rm0.z, s[3] * sc + rm0.w);
        *(float4*)(out + (size_t)n * 32 + 8 * lane + 4) =
            make_float4(s[4] * sc + rm1.x, s[5] * sc + rm1.y,
                        s[6] * sc + rm1.z, s[7] * sc + rm1.w);
    }
}

// ---------------- launch ----------------

extern "C" void kernel_launch(void* const* d_in, const int* in_sizes, int n_in,
                              void* d_out, int out_size, void* d_ws, size_t ws_size,
                              hipStream_t stream) {
    const float* x    = (const float*)d_in[0];
    const int*   src  = (const int*)d_in[1];
    const int*   dst  = (const int*)d_in[2];
    const float* W1   = (const float*)d_in[3];
    const float* al1  = (const float*)d_in[4];
    const float* ar1  = (const float*)d_in[5];
    const float* b1   = (const float*)d_in[6];
    const float* W2   = (const float*)d_in[7];
    const float* al2  = (const float*)d_in[8];
    const float* ar2  = (const float*)d_in[9];
    const float* b2   = (const float*)d_in[10];
    const float* W3   = (const float*)d_in[11];
    const float* al3  = (const float*)d_in[12];
    const float* ar3  = (const float*)d_in[13];
    const float* b3   = (const float*)d_in[14];
    const float* resW3= (const float*)d_in[15];
    float* out = (float*)d_out;

    const int N = in_sizes[0] / 128;
    const int E = in_sizes[1];
    const int TILES16 = (N + 15) / 16;
    const int PT = (TILES16 + 3) & ~3;
    const int NB = PT / 4;
    const int NSB = (N + 2047) / 2048;     // scan blocks
    const int NB16 = (TILES16 + 3) & ~3;   // 16-node groups, mult of 4 (XCD map exact)

    // workspace layout (8/16B alignment: csr_sd and el8/er8 placed before odd-sized int arrays)
    float* fws  = (float*)d_ws;
    float* elb  = fws;                           // [6][N] planes (L1/L2)
    float* erb  = elb + (size_t)N * 6;           // [6][N]
    _Float16* feat_h = (_Float16*)(erb + (size_t)N * 6);  // L1/2: [4][N][32] planes; L3: [N][192]
    _Float16* xh_hi  = feat_h + (size_t)N * 192;          // PT*2048 (x packed; reused as h2)
    _Float16* xh_lo  = xh_hi + (size_t)PT * 2048;
    _Float16* h1_hi  = xh_lo + (size_t)PT * 2048;         // h1 planes; dead after L2 agg ->
    _Float16* h1_lo  = h1_hi + (size_t)PT * 2048;         //   reused as wexp[E][6] f32
    _Float16* wts    = h1_lo + (size_t)PT * 2048;         // 122880 f16
    int2* csr_sd   = (int2*)(wts + 122880);      // [E] packed (src,dst)
    float* el8     = (float*)(csr_sd + E);       // [N][8] padded logit tables (L3)
    float* er8     = el8 + (size_t)N * 8;
    int* deg       = (int*)(er8 + (size_t)N * 8);
    int* row_start = deg + N;
    int* bsum      = row_start + (N + 1);
    int* rank      = bsum + 64;                  // [E] per-edge in-bucket rank
    float* wexp    = (float*)h1_hi;              // [E][6] f32, overlays dead h1 planes

    const _Float16* W1h = wts;
    const _Float16* W1l = wts + 16384;
    const _Float16* W2h = wts + 32768;
    const _Float16* W2l = wts + 49152;
    const _Float16* B3h = wts + 65536;          // [W3 12 tiles | resm 2 tiles]
    const _Float16* B3l = wts + 94208;

    // ---- CSR build (by dst): ONE returning-atomic pass + scan + atomic-free fill ----
    hipMemsetAsync(deg, 0, (size_t)N * sizeof(int), stream);
    hist_rank<<<dim3((E + 255) / 256), dim3(256), 0, stream>>>(dst, E, deg, rank);
    scan_phaseA<<<dim3(NSB), dim3(256), 0, stream>>>(deg, N, bsum);
    scan_phaseB<<<dim3(1), dim3(64), 0, stream>>>(bsum, NSB);
    scan_phaseC<<<dim3(NSB), dim3(256), 0, stream>>>(deg, N, bsum, row_start, E);
    fill_kernel<<<dim3((E + 255) / 256), dim3(256), 0, stream>>>(src, dst, E, row_start, rank, csr_sd);
    wsplit_all<<<dim3(240), dim3(256), 0, stream>>>(W1, W2, W3, resW3, wts);
    splitx_kernel<<<dim3((PT * 2048 + 255) / 256), dim3(256), 0, stream>>>(x, xh_hi, xh_lo, N, PT);

    // ---- Layer 1 ----
    mfma_fc<128, 4><<<dim3(NB), dim3(256), 0, stream>>>(
        xh_hi, xh_lo, W1h, W1l, al1, ar1, feat_h, elb, erb, N);
    gat_agg_q<0><<<dim3(NB16 * 4), dim3(256), 0, stream>>>(
        feat_h, elb, erb, row_start, csr_sd, b1,
        nullptr, nullptr, h1_hi, h1_lo, N, NB16);

    // ---- Layer 2 (identity residual = h1 packed planes) ----
    mfma_fc<128, 4><<<dim3(NB), dim3(256), 0, stream>>>(
        h1_hi, h1_lo, W2h, W2l, al2, ar2, feat_h, elb, erb, N);
    gat_agg_q<1><<<dim3(NB16 * 4), dim3(256), 0, stream>>>(
        feat_h, elb, erb, row_start, csr_sd, b2,
        h1_hi, h1_lo, xh_hi, xh_lo, N, NB16);   // h2 -> reuse x planes

    // ---- Layer 3: GEMM (feat + logit tables + res/bias mean -> out), wexp, mean-agg ----
    mfma_fc3<<<dim3(NB), dim3(256), 0, stream>>>(
        xh_hi, xh_lo, B3h, B3l, al3, ar3, b3, feat_h, out, el8, er8, N);
    wexp_l3<<<dim3((E + 255) / 256), dim3(256), 0, stream>>>(
        csr_sd, el8, er8, wexp, E);
    gat_agg_mean6w<<<dim3((N + 3) / 4), dim3(256), 0, stream>>>(
        feat_h, wexp, row_start, csr_sd, out, N);
}

// Round 11
// 393.978 us; speedup vs baseline: 1.0588x; 1.0093x over previous
//
#include <hip/hip_runtime.h>
#include <math.h>

// GAT 3-layer forward on MI355X.
// N=50000 nodes, E=850000 edges (incl self loops), IN=128, HID=OUT=32, HEADS=(4,4,6).
// GEMMs: split-f16 MFMA (hi/lo, 3 mfma), LDS-free; A and B pre-packed in MFMA-fragment
// order (pack_off) -> every wave load is 1KB contiguous. NEVER partial-unroll the tile
// loop (dynamic acc[] indexing -> scratch spill, round 4).
// Layer-3 residual+bias folded THROUGH the head-mean: resm = mean_h(resW3 slices) is 2
// extra B-tiles in mfma_fc3; fc3 writes res_m + mean_h(b3) DIRECTLY into d_out (full
// overwrite -> replay-idempotent); layer-3 agg ADDS the softmax mean (plain stores).
// ROUND-3 LESSON: NEVER use global fp32 atomicAdd for the head-mean (300MB WRITE, 4.5x).
// ROUND-4 LESSON: layer-3 gather must be INTERLEAVED [N][192]; head planes only pay
// when the per-XCD working set is L2-resident (L1/L2 agg).
// ROUND-5 LESSON: gather limiter = INDEPENDENT requests in flight; dependent chains
// (csr->el->exp->feat) throttle issue. wexp[E][6] precompute fixed layer-3 agg.
// ROUND-6/7/8 LESSON: returning-atomic sweep is parallelism-bound; do the returning
// atomic ONCE (hist_rank keeps the return as in-bucket rank), fill is then ZERO-atomic.
// ROUND-9 LESSON: unroll deeper than 4x REGRESSES (tail dominates at avg deg 17);
// 4x main + 2x mid-tail + 1x tail is the sweet spot. Per-wave MLP is exhausted.
// ROUND-11: csr is SRC-ONLY (4B/edge). The aggs never need dst (round-10 PMC: agg_q
// streamed 27MB of int2 using only .x -> half wasted, re-streamed once per head);
// wexp derives dst from CSR position (node-parallel wexp_node, er8 row broadcast per
// node). fill writes half the data (same random-sector count).
// Aggregation L1/L2: QUARTER-WAVE head-split (16 lanes/(node,head), 4 lanes/edge, G=4),
// feat head planes [H][N][32] f16 + el/er planes [H][N], XCD-pinned (blockIdx%8 -> XCD,
// head-major order) -> compulsory fetch. Round-1 lesson: 1 wave/(node,head) = 4x waves
// = overhead-bound. All cross-lane shuffles execute unconditionally; stores guarded.
// CSR prefix scan: 3-phase multi-block.

typedef _Float16 v8h __attribute__((ext_vector_type(8)));
typedef float f32x4 __attribute__((ext_vector_type(4)));

// packed fragment offset for row n, k-dim k (128-wide K):
__device__ __host__ inline int pack_off(int n, int k) {
    return ((n >> 4) << 11) | ((k >> 5) << 9) | (((k >> 3) & 3) << 7) | ((n & 15) << 3) | (k & 7);
}

// ---------------- CSR build (by dst) ----------------

// ONE returning-atomic pass: deg histogram AND per-edge in-bucket rank.
__global__ void hist_rank(const int* __restrict__ dst, int E,
                          int* __restrict__ deg, int* __restrict__ rank) {
    int i = blockIdx.x * blockDim.x + threadIdx.x;
    if (i < E) rank[i] = atomicAdd(&deg[dst[i]], 1);
}

__global__ void scan_phaseA(const int* __restrict__ deg, int n, int* __restrict__ bsum) {
    __shared__ int red[4];
    int t = threadIdx.x;
    int base = blockIdx.x * 2048 + t * 8;
    int s = 0;
    #pragma unroll
    for (int q = 0; q < 8; q++) { int i = base + q; if (i < n) s += deg[i]; }
    #pragma unroll
    for (int off = 1; off < 64; off <<= 1) s += __shfl_xor(s, off);
    if ((t & 63) == 0) red[t >> 6] = s;
    __syncthreads();
    if (t == 0) bsum[blockIdx.x] = red[0] + red[1] + red[2] + red[3];
}

__global__ void scan_phaseB(int* __restrict__ bsum, int nb) {
    int lane = threadIdx.x & 63;
    int v = (lane < nb) ? bsum[lane] : 0;
    int inc = v;
    #pragma unroll
    for (int off = 1; off < 64; off <<= 1) {
        int u = __shfl_up(inc, off);
        if (lane >= off) inc += u;
    }
    int ex = inc - v;
    if (lane < nb) bsum[lane] = ex;
}

__global__ void scan_phaseC(const int* __restrict__ deg, int n, const int* __restrict__ bsum,
                            int* __restrict__ row_start, int E) {
    __shared__ int wsum[4];
    int t = threadIdx.x;
    int lane = t & 63, wv = t >> 6;
    int base = blockIdx.x * 2048 + t * 8;
    int v[8]; int s = 0;
    #pragma unroll
    for (int q = 0; q < 8; q++) { int i = base + q; v[q] = (i < n) ? deg[i] : 0; s += v[q]; }
    int inc = s;
    #pragma unroll
    for (int off = 1; off < 64; off <<= 1) {
        int u = __shfl_up(inc, off);
        if (lane >= off) inc += u;
    }
    if (lane == 63) wsum[wv] = inc;
    __syncthreads();
    int woff = 0;
    for (int w = 0; w < wv; w++) woff += wsum[w];
    int run = inc - s + woff + bsum[blockIdx.x];
    #pragma unroll
    for (int q = 0; q < 8; q++) {
        int i = base + q;
        if (i < n) row_start[i] = run;
        run += v[q];
    }
    if (blockIdx.x == 0 && t == 0) row_start[n] = E;
}

// ZERO-atomic fill: position = row_start[d] (L2-resident gather) + rank[i] (stream).
// SRC-ONLY 4B scattered store (round 11: aggs never need dst; wexp derives it).
__global__ void fill_kernel(const int* __restrict__ src, const int* __restrict__ dst, int E,
                            const int* __restrict__ row_start, const int* __restrict__ rank,
                            int* __restrict__ csr_src) {
    int i = blockIdx.x * blockDim.x + threadIdx.x;
    if (i < E) {
        int s = src[i], d = dst[i];
        int at = row_start[d] + rank[i];
        csr_src[at] = s;
    }
}

// ---------------- weight hi/lo split into PACKED fragment layout ----------------
// Regions: W1 (128c x 128k), W2 (128c x 128k), B3 = [W3 192c | resm 32c] x 128k.
// resm[k][c] = mean over 6 heads of resW3[k][h*32+c]  (residual folded through head-mean).

__global__ void wsplit_all(const float* __restrict__ W1, const float* __restrict__ W2,
                           const float* __restrict__ W3, const float* __restrict__ Wr,
                           _Float16* __restrict__ o) {
    int i = blockIdx.x * blockDim.x + threadIdx.x;
    if (i >= 61440) return;
    float v; int ohi, stride, po;
    if (i < 16384) {
        int e = i, c = e >> 7, k = e & 127;
        v = W1[(size_t)k * 128 + c]; ohi = 0; stride = 16384; po = pack_off(c, k);
    } else if (i < 32768) {
        int e = i - 16384, c = e >> 7, k = e & 127;
        v = W2[(size_t)k * 128 + c]; ohi = 32768; stride = 16384; po = pack_off(c, k);
    } else if (i < 57344) {
        int e = i - 32768, c = e >> 7, k = e & 127;
        v = W3[(size_t)k * 192 + c]; ohi = 65536; stride = 28672; po = pack_off(c, k);
    } else {
        int e = i - 57344, c = e >> 7, k = e & 127;
        float s = 0.f;
        #pragma unroll
        for (int h = 0; h < 6; h++) s += Wr[(size_t)k * 192 + h * 32 + c];
        v = s * (1.0f / 6.0f);
        ohi = 65536; stride = 28672; po = 24576 + pack_off(c, k);
    }
    _Float16 hv = (_Float16)v;
    o[ohi + po] = hv;
    o[ohi + stride + po] = (_Float16)(v - (float)hv);
}

// ---------------- x -> packed hi/lo f16 fragment layout ----------------

__global__ void splitx_kernel(const float* __restrict__ x, _Float16* __restrict__ hi,
                              _Float16* __restrict__ lo, int N, int PT) {
    int i = blockIdx.x * blockDim.x + threadIdx.x;
    if (i >= PT * 2048) return;
    int mt = i >> 11, r = i & 2047;
    int q4 = r >> 9, quad = (r >> 7) & 3, ln = (r >> 3) & 15, j = r & 7;
    int n = mt * 16 + ln, k = q4 * 32 + quad * 8 + j;
    float v = (n < N) ? x[(size_t)n * 128 + k] : 0.f;
    _Float16 h = (_Float16)v;
    hi[i] = h;
    lo[i] = (_Float16)(v - (float)h);
}

// ---------------- LDS-free MFMA fc (+ attention logits), layers 1/2 ----------------
// feat_out is HEAD-MAJOR PLANES: [H][N][32] f16; el/er are planes [H][N].

template <int CC, int H>
__global__ __launch_bounds__(256, 4) void mfma_fc(
    const _Float16* __restrict__ Ahi, const _Float16* __restrict__ Alo,
    const _Float16* __restrict__ Bhi, const _Float16* __restrict__ Blo,
    const float* __restrict__ al, const float* __restrict__ ar,
    _Float16* __restrict__ feat_out,
    float* __restrict__ el, float* __restrict__ er, int N) {
    constexpr int TILES = CC / 16;
    int t = threadIdx.x;
    int wave = t >> 6, lane = t & 63;
    int ln = lane & 15, quad = lane >> 4;
    int mt = blockIdx.x * 4 + wave;

    f32x4 acc[TILES];
    #pragma unroll
    for (int i = 0; i < TILES; i++) acc[i] = (f32x4){0.f, 0.f, 0.f, 0.f};

    const _Float16* pa_h = Ahi + (size_t)mt * 2048 + lane * 8;
    const _Float16* pa_l = Alo + (size_t)mt * 2048 + lane * 8;

    #pragma unroll
    for (int q4 = 0; q4 < 4; q4++) {
        v8h ah = *(const v8h*)(pa_h + q4 * 512);
        v8h av = *(const v8h*)(pa_l + q4 * 512);
        #pragma unroll
        for (int tt = 0; tt < TILES; tt++) {
            size_t boff = (size_t)tt * 2048 + q4 * 512 + lane * 8;
            v8h bh = *(const v8h*)(Bhi + boff);
            v8h bl = *(const v8h*)(Blo + boff);
            acc[tt] = __builtin_amdgcn_mfma_f32_16x16x32_f16(av, bh, acc[tt], 0, 0, 0);
            acc[tt] = __builtin_amdgcn_mfma_f32_16x16x32_f16(ah, bl, acc[tt], 0, 0, 0);
            acc[tt] = __builtin_amdgcn_mfma_f32_16x16x32_f16(ah, bh, acc[tt], 0, 0, 0);
        }
    }

    #pragma unroll
    for (int tt = 0; tt < TILES; tt++) {
        int n = tt * 16 + ln;
        int head = n >> 5, wi = n & 31;
        _Float16* fo = feat_out + (size_t)head * N * 32;
        #pragma unroll
        for (int r = 0; r < 4; r++) {
            int m = mt * 16 + quad * 4 + r;
            if (m < N) fo[(size_t)m * 32 + wi] = (_Float16)acc[tt][r];
        }
    }
    #pragma unroll
    for (int hg = 0; hg < H; hg++) {
        float a0 = al[hg * 32 + ln], a1 = al[hg * 32 + 16 + ln];
        float r0 = ar[hg * 32 + ln], r1 = ar[hg * 32 + 16 + ln];
        #pragma unroll
        for (int r = 0; r < 4; r++) {
            float pl = acc[2 * hg][r] * a0 + acc[2 * hg + 1][r] * a1;
            float pr = acc[2 * hg][r] * r0 + acc[2 * hg + 1][r] * r1;
            #pragma unroll
            for (int off = 1; off < 16; off <<= 1) {
                pl += __shfl_xor(pl, off);
                pr += __shfl_xor(pr, off);
            }
            int m = mt * 16 + quad * 4 + r;
            if (ln == 0 && m < N) {
                el[(size_t)hg * N + m] = pl;
                er[(size_t)hg * N + m] = pr;
            }
        }
    }
}

// ---------------- layer 3: single pass, 14 tiles ----------------
// Tiles 0..11 = W3 feat -> INTERLEAVED [N][192] f16 (round-4 lesson). Tiles 12..13 =
// res-mean fp32, written (+ mean_h(b3)) DIRECTLY into d_out; agg then ADDS softmax mean.
// Logits go to PADDED [N][8] tables el8/er8 (32B rows, L2-resident for wexp_node).

__global__ __launch_bounds__(256, 3) void mfma_fc3(
    const _Float16* __restrict__ Ahi, const _Float16* __restrict__ Alo,
    const _Float16* __restrict__ Bhi, const _Float16* __restrict__ Blo,
    const float* __restrict__ al, const float* __restrict__ ar,
    const float* __restrict__ b3,
    _Float16* __restrict__ feat_out, float* __restrict__ out,
    float* __restrict__ el8, float* __restrict__ er8, int N) {
    constexpr int H = 6, TILES = 14;
    int t = threadIdx.x;
    int wave = t >> 6, lane = t & 63;
    int ln = lane & 15, quad = lane >> 4;
    int mt = blockIdx.x * 4 + wave;

    f32x4 acc[TILES];
    #pragma unroll
    for (int i = 0; i < TILES; i++) acc[i] = (f32x4){0.f, 0.f, 0.f, 0.f};

    const _Float16* pa_h = Ahi + (size_t)mt * 2048 + lane * 8;
    const _Float16* pa_l = Alo + (size_t)mt * 2048 + lane * 8;

    #pragma unroll
    for (int q4 = 0; q4 < 4; q4++) {
        v8h ah = *(const v8h*)(pa_h + q4 * 512);
        v8h av = *(const v8h*)(pa_l + q4 * 512);
        #pragma unroll
        for (int tt = 0; tt < TILES; tt++) {
            size_t boff = (size_t)tt * 2048 + q4 * 512 + lane * 8;
            v8h bh = *(const v8h*)(Bhi + boff);
            v8h bl = *(const v8h*)(Blo + boff);
            acc[tt] = __builtin_amdgcn_mfma_f32_16x16x32_f16(av, bh, acc[tt], 0, 0, 0);
            acc[tt] = __builtin_amdgcn_mfma_f32_16x16x32_f16(ah, bl, acc[tt], 0, 0, 0);
            acc[tt] = __builtin_amdgcn_mfma_f32_16x16x32_f16(ah, bh, acc[tt], 0, 0, 0);
        }
    }

    #pragma unroll
    for (int tt = 0; tt < 12; tt++) {
        int n = tt * 16 + ln;
        #pragma unroll
        for (int r = 0; r < 4; r++) {
            int m = mt * 16 + quad * 4 + r;
            if (m < N) feat_out[(size_t)m * 192 + n] = (_Float16)acc[tt][r];
        }
    }
    #pragma unroll
    for (int tt = 12; tt < 14; tt++) {
        int n32 = (tt - 12) * 16 + ln;
        float bm = (b3[n32] + b3[32 + n32] + b3[64 + n32] + b3[96 + n32] +
                    b3[128 + n32] + b3[160 + n32]) * (1.0f / 6.0f);
        #pragma unroll
        for (int r = 0; r < 4; r++) {
            int m = mt * 16 + quad * 4 + r;
            if (m < N) out[(size_t)m * 32 + n32] = acc[tt][r] + bm;
        }
    }
    #pragma unroll
    for (int hg = 0; hg < H; hg++) {
        float a0 = al[hg * 32 + ln], a1 = al[hg * 32 + 16 + ln];
        float r0 = ar[hg * 32 + ln], r1 = ar[hg * 32 + 16 + ln];
        #pragma unroll
        for (int r = 0; r < 4; r++) {
            float pl = acc[2 * hg][r] * a0 + acc[2 * hg + 1][r] * a1;
            float pr = acc[2 * hg][r] * r0 + acc[2 * hg + 1][r] * r1;
            #pragma unroll
            for (int off = 1; off < 16; off <<= 1) {
                pl += __shfl_xor(pl, off);
                pr += __shfl_xor(pr, off);
            }
            int m = mt * 16 + quad * 4 + r;
            if (ln == 0 && m < N) {
                el8[(size_t)m * 8 + hg] = pl;
                er8[(size_t)m * 8 + hg] = pr;
            }
        }
    }
}

// ---------------- layer-3 edge weights, NODE-PARALLEL: dst = CSR row ----------------
// Quarter-wave per node (16 lanes, edges strided by 16). er8 row read once per node
// (broadcast); el8 gather per edge hits the 1.6MB L2-resident table; writes are
// contiguous 24B per edge (coalesced within a node's range). No csr_dst needed.

__global__ __launch_bounds__(256) void wexp_node(
        const int* __restrict__ csr_src, const int* __restrict__ row_start,
        const float* __restrict__ el8, const float* __restrict__ er8,
        float* __restrict__ wexp, int N) {
    int wv = threadIdx.x >> 6, lane = threadIdx.x & 63;
    int sub = lane >> 4;       // node within wave (0..3)
    int l   = lane & 15;       // edge lane
    int n = (blockIdx.x * 4 + wv) * 4 + sub;
    if (n >= N) return;
    int start = row_start[n], end = row_start[n + 1];
    float4 b0 = *(const float4*)(er8 + (size_t)n * 8);
    float2 b1 = *(const float2*)(er8 + (size_t)n * 8 + 4);
    for (int j = start + l; j < end; j += 16) {
        int s = csr_src[j];
        float4 a0 = *(const float4*)(el8 + (size_t)s * 8);
        float2 a1 = *(const float2*)(el8 + (size_t)s * 8 + 4);
        float e[6] = {a0.x + b0.x, a0.y + b0.y, a0.z + b0.z, a0.w + b0.w,
                      a1.x + b1.x, a1.y + b1.y};
        float* wp = wexp + (size_t)j * 6;
        #pragma unroll
        for (int h = 0; h < 6; h++) {
            float v = e[h];
            v = (v >= 0.f) ? v : 0.2f * v;
            wp[h] = __expf(v);
        }
    }
}

// ---------------- layers 1/2 aggregate: QUARTER-WAVE HEAD-SPLIT, XCD-PINNED ----------------
// Block = 256 thr = 4 waves; wave covers 4 (node,head) slices of 16 lanes. Slice lane:
// q = sl&3 (dim quad: dims h*32+8q..+7), g = sl>>2 (edge group 0..3). 2x-unrolled edge
// loop (round-8 proven; deeper regresses at avg deg 17). Reduce = 2 shuffle stages.
// Block->task map uses hardware round-robin (blockIdx%8 -> XCD): t=(b&7)*C+(b>>3);
// h=t/NB16 (head-major order => each XCD streams one 3.2MB plane at a time).
// RES: 0 none, 1 packed hi/lo identity residual. Output: relu + packed hi/lo planes.
// All shuffles unconditional; loads clamped, stores guarded.

template <int RES>
__global__ __launch_bounds__(256) void gat_agg_q(
        const _Float16* __restrict__ feat_planes, const float* __restrict__ el,
        const float* __restrict__ er, const int* __restrict__ row_start,
        const int* __restrict__ csr_src, const float* __restrict__ bias,
        const _Float16* __restrict__ res_hi, const _Float16* __restrict__ res_lo,
        _Float16* __restrict__ out_hi, _Float16* __restrict__ out_lo,
        int N, int NB16) {
    constexpr int H = 4;
    unsigned b = blockIdx.x;
    unsigned C = (unsigned)(NB16 * H) >> 3;       // blocks per XCD (NB16%2==0 => exact)
    unsigned t = (b & 7u) * C + (b >> 3);
    int h  = (int)(t / (unsigned)NB16);
    int ng = (int)(t - (unsigned)h * (unsigned)NB16);
    int wv = threadIdx.x >> 6, lane = threadIdx.x & 63;
    int slice = lane >> 4, sl = lane & 15;
    int q = sl & 3;          // dim quad
    int g = sl >> 2;         // edge group 0..3
    int n = ng * 16 + wv * 4 + slice;
    bool valid = (n < N);
    int nc = valid ? n : (N - 1);

    int start = row_start[nc];
    int end   = valid ? row_start[nc + 1] : start;
    float er_h = er[(size_t)h * N + nc];
    const float* el_h = el + (size_t)h * N;
    const _Float16* fbase = feat_planes + (size_t)h * N * 32 + q * 8;

    float acc[8];
    #pragma unroll
    for (int i = 0; i < 8; i++) acc[i] = 0.f;
    float wsum = 0.f;

    int j = start + g;
    for (; j + 4 < end; j += 8) {
        int s0 = csr_src[j];
        int s1 = csr_src[j + 4];
        float e0 = el_h[s0] + er_h;
        float e1 = el_h[s1] + er_h;
        e0 = (e0 >= 0.f) ? e0 : 0.2f * e0;
        e1 = (e1 >= 0.f) ? e1 : 0.2f * e1;
        float w0 = __expf(e0);
        float w1 = __expf(e1);
        v8h v0 = *(const v8h*)(fbase + (size_t)s0 * 32);
        v8h v1 = *(const v8h*)(fbase + (size_t)s1 * 32);
        wsum += w0 + w1;
        #pragma unroll
        for (int i = 0; i < 8; i++) acc[i] += w0 * (float)v0[i] + w1 * (float)v1[i];
    }
    if (j < end) {
        int s0 = csr_src[j];
        float e0 = el_h[s0] + er_h;
        e0 = (e0 >= 0.f) ? e0 : 0.2f * e0;
        float w0 = __expf(e0);
        v8h v0 = *(const v8h*)(fbase + (size_t)s0 * 32);
        wsum += w0;
        #pragma unroll
        for (int i = 0; i < 8; i++) acc[i] += w0 * (float)v0[i];
    }

    // reduce across the 4 edge groups (sl bits 2,3) -- unconditional
    #pragma unroll
    for (int off = 4; off < 16; off <<= 1) {
        #pragma unroll
        for (int i = 0; i < 8; i++) acc[i] += __shfl_xor(acc[i], off);
        wsum += __shfl_xor(wsum, off);
    }

    float inv = 1.0f / fmaxf(wsum, 1e-9f);
    float4 bv0 = *(const float4*)(bias + h * 32 + q * 8);
    float4 bv1 = *(const float4*)(bias + h * 32 + q * 8 + 4);
    float r[8];
    r[0] = acc[0] * inv + bv0.x; r[1] = acc[1] * inv + bv0.y;
    r[2] = acc[2] * inv + bv0.z; r[3] = acc[3] * inv + bv0.w;
    r[4] = acc[4] * inv + bv1.x; r[5] = acc[5] * inv + bv1.y;
    r[6] = acc[6] * inv + bv1.z; r[7] = acc[7] * inv + bv1.w;

    if constexpr (RES == 1) {
        int off = pack_off(nc, h * 32 + q * 8);
        v8h rh = *(const v8h*)(res_hi + off);
        v8h rl = *(const v8h*)(res_lo + off);
        #pragma unroll
        for (int i = 0; i < 8; i++) r[i] += (float)rh[i] + (float)rl[i];
    }
    #pragma unroll
    for (int i = 0; i < 8; i++) r[i] = fmaxf(r[i], 0.f);

    if (g == 0 && valid) {
        int po = pack_off(n, h * 32 + q * 8);
        v8h hh, ll;
        #pragma unroll
        for (int i = 0; i < 8; i++) {
            hh[i] = (_Float16)r[i];
            ll[i] = (_Float16)(r[i] - (float)hh[i]);
        }
        *(v8h*)(out_hi + po) = hh;
        *(v8h*)(out_lo + po) = ll;
    }
}

// ---------------- layer 3 aggregate: precomputed weights, INTERLEAVED gather ----------------
// 24 dim-lanes (lane d8: dims 8*d8..+7 of the 192-dim row; hd = d8>>2), G=2 edge groups,
// 4x-unrolled main + 2x mid-tail + 1x tail (round-9 lesson). Hot loop: csr_src (stream)
// + wexp (stream) + ONE dependent feat gather -- no el load, no exp (round-5 lesson).
// fc3 prefilled out with res_mean + mean_h(b3); ADDS mean_h(acc*inv), plain stores
// (NO atomics, round-3 lesson). Shuffles unconditional; stores guarded (lane<4).

__global__ __launch_bounds__(256) void gat_agg_mean6w(
        const _Float16* __restrict__ feat, const float* __restrict__ wexp,
        const int* __restrict__ row_start, const int* __restrict__ csr_src,
        float* __restrict__ out, int N) {
    constexpr int H = 6, ROW = 192, LPG = 24, G = 2;
    int wv = threadIdx.x >> 6, lane = threadIdx.x & 63;
    int n = blockIdx.x * 4 + wv;
    if (n >= N) return;

    int d8 = lane % LPG;
    int g  = lane / LPG;      // 0,1 active; 2 idle in gather
    int hd = d8 >> 2, qb = d8 & 3;

    int start = row_start[n], end = row_start[n + 1];
    const _Float16* fbase = feat + 8 * d8;

    float acc[8];
    #pragma unroll
    for (int q = 0; q < 8; q++) acc[q] = 0.f;
    float wsum = 0.f;

    int j = (g < G) ? (start + g) : end;
    for (; j + 3 * G < end; j += 4 * G) {
        int s0 = csr_src[j];
        int s1 = csr_src[j + G];
        int s2 = csr_src[j + 2 * G];
        int s3 = csr_src[j + 3 * G];
        float w0 = wexp[(size_t)j * 6 + hd];
        float w1 = wexp[(size_t)(j + G) * 6 + hd];
        float w2 = wexp[(size_t)(j + 2 * G) * 6 + hd];
        float w3 = wexp[(size_t)(j + 3 * G) * 6 + hd];
        v8h v0 = *(const v8h*)(fbase + (size_t)s0 * ROW);
        v8h v1 = *(const v8h*)(fbase + (size_t)s1 * ROW);
        v8h v2 = *(const v8h*)(fbase + (size_t)s2 * ROW);
        v8h v3 = *(const v8h*)(fbase + (size_t)s3 * ROW);
        wsum += (w0 + w1) + (w2 + w3);
        #pragma unroll
        for (int q = 0; q < 8; q++)
            acc[q] += (w0 * (float)v0[q] + w1 * (float)v1[q]) +
                      (w2 * (float)v2[q] + w3 * (float)v3[q]);
    }
    // 2x mid-tail: keeps 2 gathers in flight for the first part of the remainder
    for (; j + G < end; j += 2 * G) {
        int s0 = csr_src[j];
        int s1 = csr_src[j + G];
        float w0 = wexp[(size_t)j * 6 + hd];
        float w1 = wexp[(size_t)(j + G) * 6 + hd];
        v8h v0 = *(const v8h*)(fbase + (size_t)s0 * ROW);
        v8h v1 = *(const v8h*)(fbase + (size_t)s1 * ROW);
        wsum += w0 + w1;
        #pragma unroll
        for (int q = 0; q < 8; q++)
            acc[q] += w0 * (float)v0[q] + w1 * (float)v1[q];
    }
    if (j < end) {
        int s0 = csr_src[j];
        float w0 = wexp[(size_t)j * 6 + hd];
        v8h v0 = *(const v8h*)(fbase + (size_t)s0 * ROW);
        wsum += w0;
        #pragma unroll
        for (int q = 0; q < 8; q++) acc[q] += w0 * (float)v0[q];
    }

    // cross-group combine (G == 2, LPG == 24: partner lane +24), unconditional
    #pragma unroll
    for (int q = 0; q < 8; q++) acc[q] += __shfl(acc[q], lane + 24);
    wsum += __shfl(wsum, lane + 24);

    float inv = 1.0f / fmaxf(wsum, 1e-9f);
    float r[8];
    #pragma unroll
    for (int q = 0; q < 8; q++) r[q] = acc[q] * inv;

    // head-mean: lane d8 = hd*4 + qb; sum over heads from lanes qb+4*hh, unconditional
    float s[8];
    #pragma unroll
    for (int q = 0; q < 8; q++) {
        s[q] = r[q];
        #pragma unroll
        for (int hh2 = 1; hh2 < H; hh2++) s[q] += __shfl(r[q], qb + 4 * hh2);
    }
    if (lane < 4) {
        const float sc = 1.0f / 6.0f;
        float4 rm0 = *(const float4*)(out + (size_t)n * 32 + 8 * lane);
        float4 rm1 = *(const float4*)(out + (size_t)n * 32 + 8 * lane + 4);
        *(float4*)(out + (size_t)n * 32 + 8 * lane) =
            make_float4(s[0] * sc + rm0.x, s[1] * sc + rm0.y,
                        s[2] * sc + rm0.z, s[3] * sc + rm0.w);
        *(float4*)(out + (size_t)n * 32 + 8 * lane + 4) =
            make_float4(s[4] * sc + rm1.x, s[5] * sc + rm1.y,
                        s[6] * sc + rm1.z, s[7] * sc + rm1.w);
    }
}

// ---------------- launch ----------------

extern "C" void kernel_launch(void* const* d_in, const int* in_sizes, int n_in,
                              void* d_out, int out_size, void* d_ws, size_t ws_size,
                              hipStream_t stream) {
    const float* x    = (const float*)d_in[0];
    const int*   src  = (const int*)d_in[1];
    const int*   dst  = (const int*)d_in[2];
    const float* W1   = (const float*)d_in[3];
    const float* al1  = (const float*)d_in[4];
    const float* ar1  = (const float*)d_in[5];
    const float* b1   = (const float*)d_in[6];
    const float* W2   = (const float*)d_in[7];
    const float* al2  = (const float*)d_in[8];
    const float* ar2  = (const float*)d_in[9];
    const float* b2   = (const float*)d_in[10];
    const float* W3   = (const float*)d_in[11];
    const float* al3  = (const float*)d_in[12];
    const float* ar3  = (const float*)d_in[13];
    const float* b3   = (const float*)d_in[14];
    const float* resW3= (const float*)d_in[15];
    float* out = (float*)d_out;

    const int N = in_sizes[0] / 128;
    const int E = in_sizes[1];
    const int Epad = (E + 3) & ~3;         // keep el8 16B-aligned after csr_src
    const int TILES16 = (N + 15) / 16;
    const int PT = (TILES16 + 3) & ~3;
    const int NB = PT / 4;
    const int NSB = (N + 2047) / 2048;     // scan blocks
    const int NB16 = (TILES16 + 3) & ~3;   // 16-node groups, mult of 4 (XCD map exact)

    // workspace layout (16B alignment maintained for el8/er8 float4 reads)
    float* fws  = (float*)d_ws;
    float* elb  = fws;                           // [6][N] planes (L1/L2)
    float* erb  = elb + (size_t)N * 6;           // [6][N]
    _Float16* feat_h = (_Float16*)(erb + (size_t)N * 6);  // L1/2: [4][N][32] planes; L3: [N][192]
    _Float16* xh_hi  = feat_h + (size_t)N * 192;          // PT*2048 (x packed; reused as h2)
    _Float16* xh_lo  = xh_hi + (size_t)PT * 2048;
    _Float16* h1_hi  = xh_lo + (size_t)PT * 2048;         // h1 planes; dead after L2 agg ->
    _Float16* h1_lo  = h1_hi + (size_t)PT * 2048;         //   reused as wexp[E][6] f32
    _Float16* wts    = h1_lo + (size_t)PT * 2048;         // 122880 f16
    int* csr_src   = (int*)(wts + 122880);       // [Epad] src-only CSR (round 11)
    float* el8     = (float*)(csr_src + Epad);   // [N][8] padded logit tables (L3)
    float* er8     = el8 + (size_t)N * 8;
    int* deg       = (int*)(er8 + (size_t)N * 8);
    int* row_start = deg + N;
    int* bsum      = row_start + (N + 1);
    int* rank      = bsum + 64;                  // [E] per-edge in-bucket rank
    float* wexp    = (float*)h1_hi;              // [E][6] f32, overlays dead h1 planes

    const _Float16* W1h = wts;
    const _Float16* W1l = wts + 16384;
    const _Float16* W2h = wts + 32768;
    const _Float16* W2l = wts + 49152;
    const _Float16* B3h = wts + 65536;          // [W3 12 tiles | resm 2 tiles]
    const _Float16* B3l = wts + 94208;

    // ---- CSR build (by dst): ONE returning-atomic pass + scan + atomic-free fill ----
    hipMemsetAsync(deg, 0, (size_t)N * sizeof(int), stream);
    hist_rank<<<dim3((E + 255) / 256), dim3(256), 0, stream>>>(dst, E, deg, rank);
    scan_phaseA<<<dim3(NSB), dim3(256), 0, stream>>>(deg, N, bsum);
    scan_phaseB<<<dim3(1), dim3(64), 0, stream>>>(bsum, NSB);
    scan_phaseC<<<dim3(NSB), dim3(256), 0, stream>>>(deg, N, bsum, row_start, E);
    fill_kernel<<<dim3((E + 255) / 256), dim3(256), 0, stream>>>(src, dst, E, row_start, rank, csr_src);
    wsplit_all<<<dim3(240), dim3(256), 0, stream>>>(W1, W2, W3, resW3, wts);
    splitx_kernel<<<dim3((PT * 2048 + 255) / 256), dim3(256), 0, stream>>>(x, xh_hi, xh_lo, N, PT);

    // ---- Layer 1 ----
    mfma_fc<128, 4><<<dim3(NB), dim3(256), 0, stream>>>(
        xh_hi, xh_lo, W1h, W1l, al1, ar1, feat_h, elb, erb, N);
    gat_agg_q<0><<<dim3(NB16 * 4), dim3(256), 0, stream>>>(
        feat_h, elb, erb, row_start, csr_src, b1,
        nullptr, nullptr, h1_hi, h1_lo, N, NB16);

    // ---- Layer 2 (identity residual = h1 packed planes) ----
    mfma_fc<128, 4><<<dim3(NB), dim3(256), 0, stream>>>(
        h1_hi, h1_lo, W2h, W2l, al2, ar2, feat_h, elb, erb, N);
    gat_agg_q<1><<<dim3(NB16 * 4), dim3(256), 0, stream>>>(
        feat_h, elb, erb, row_start, csr_src, b2,
        h1_hi, h1_lo, xh_hi, xh_lo, N, NB16);   // h2 -> reuse x planes

    // ---- Layer 3: GEMM (feat + logit tables + res/bias mean -> out), wexp, mean-agg ----
    mfma_fc3<<<dim3(NB), dim3(256), 0, stream>>>(
        xh_hi, xh_lo, B3h, B3l, al3, ar3, b3, feat_h, out, el8, er8, N);
    wexp_node<<<dim3((N + 15) / 16), dim3(256), 0, stream>>>(
        csr_src, row_start, el8, er8, wexp, N);
    gat_agg_mean6w<<<dim3((N + 3) / 4), dim3(256), 0, stream>>>(
        feat_h, wexp, row_start, csr_src, out, N);
}